// Round 5
// baseline (1533.324 us; speedup 1.0000x reference)
//
#include <hip/hip_runtime.h>
#include <hip/hip_bf16.h>
#include <stdint.h>

// ---------------- problem constants ----------------
#define BATCH   2
#define SEQL    4096
#define DMODEL  1024
#define DIN     2048          // d_inner
#define NH      32
#define HDIM    64
#define DSTATE  128
#define CONVD   2304          // d_inner + 2*d_state
#define DPROJ   4384          // 2*d_inner + 2*d_state + nheads
#define NTOT    8192          // BATCH*SEQL
#define NBIG    6528          // padded: 4384 + 1024 + 1024 = 6432 -> 6528 (/128)
#define NREAL   6432
#define NPAD    6656          // Bt rows padded to /256 for the 256-tile GEMM
#define CHT     128           // SSD chunk length
#define NCH     32            // chunks per batch-sequence (4096/128)
#define SP      136           // padded LDS row stride for scan kernels
#define CTOK    16            // conv strip length (tokens per block)
// Z (bf16) column layout: [0,2048)=z  [2048,4352)=xBC  [4352,4384)=dt
//   [4384,5408)=P (xn@Mzero)  [5408,6432)=Q (xn@Mone)
// After cumsum pass2: fp32 cumsum(Q) occupies bytes [0,4096) of each row.

typedef __attribute__((ext_vector_type(8))) short short8;
typedef __attribute__((ext_vector_type(4))) float f32x4;

__device__ __forceinline__ unsigned short f2bf(float f) {
    unsigned int u = __builtin_bit_cast(unsigned int, f);
    return (unsigned short)((u + 0x7FFFu + ((u >> 16) & 1u)) >> 16);
}
__device__ __forceinline__ float bf2f(unsigned short u) {
    unsigned int v = ((unsigned int)u) << 16;
    return __builtin_bit_cast(float, v);
}

__device__ __forceinline__ void gload16(const void* g, void* l) {
    __builtin_amdgcn_global_load_lds(
        (const __attribute__((address_space(1))) unsigned int*)g,
        (__attribute__((address_space(3))) unsigned int*)l,
        16, 0, 0);
}

// ---------------- weight prep ----------------
__global__ void transpose_cast_kernel(const float* __restrict__ in,
                                      unsigned short* __restrict__ out,
                                      int R, int C) {
    __shared__ float tile[32][33];
    int c0 = blockIdx.x * 32, r0 = blockIdx.y * 32;
    int tx = threadIdx.x, ty = threadIdx.y;
    #pragma unroll
    for (int i = ty; i < 32; i += 8)
        tile[i][tx] = in[(size_t)(r0 + i) * C + c0 + tx];
    __syncthreads();
    #pragma unroll
    for (int i = ty; i < 32; i += 8)
        out[(size_t)(c0 + i) * R + r0 + tx] = f2bf(tile[tx][i]);
}

__global__ void cast_bf16_kernel(const float* __restrict__ in,
                                 unsigned short* __restrict__ out, int n4) {
    int i = (blockIdx.x * 256 + threadIdx.x) * 4;
    if (i < n4) {
        float4 v = *(const float4*)(in + i);
        ushort4 o;
        o.x = f2bf(v.x); o.y = f2bf(v.y); o.z = f2bf(v.z); o.w = f2bf(v.w);
        *(ushort4*)(out + i) = o;
    }
}

__global__ void zero_pad_kernel(unsigned short* __restrict__ p, int n) {
    int i = blockIdx.x * 256 + threadIdx.x;
    if (i < n) p[i] = 0;
}

// ---------------- rmsnorm + cast ----------------
__global__ __launch_bounds__(256) void rmsnorm_cast_kernel(
    const float* __restrict__ x, const float* __restrict__ w,
    unsigned short* __restrict__ xn) {
    int tok = blockIdx.x, tid = threadIdx.x;
    float4 v = ((const float4*)(x + (size_t)tok * DMODEL))[tid];
    float ss = v.x*v.x + v.y*v.y + v.z*v.z + v.w*v.w;
    #pragma unroll
    for (int off = 32; off > 0; off >>= 1) ss += __shfl_xor(ss, off, 64);
    __shared__ float sred[4];
    if ((tid & 63) == 0) sred[tid >> 6] = ss;
    __syncthreads();
    float tot = sred[0] + sred[1] + sred[2] + sred[3];
    float r = rsqrtf(tot * (1.0f / DMODEL) + 1e-5f);
    float4 wv = ((const float4*)w)[tid];
    ushort4 o;
    o.x = f2bf(v.x * r * wv.x); o.y = f2bf(v.y * r * wv.y);
    o.z = f2bf(v.z * r * wv.z); o.w = f2bf(v.w * r * wv.w);
    ((ushort4*)(xn + (size_t)tok * DMODEL))[tid] = o;
}

// ================= 256x256 GEMM (bf16 out): C = A @ B^T ====================
// R5: 4-slot LDS ring (64 KB) -> 2 blocks/CU co-resident. R4's analysis:
// with 1 block/CU all 8 waves are barrier-locked into the same phase, so
// the ds_read window and the MFMA window never overlap (~2600 cyc/tile of
// sync dead time). Two phase-shifted blocks per CU fill each other's gaps
// (m97/m114: co-resident-block overlap beats source pipelining).
// Schedule (lookahead 2 halves, ONE barrier/phase):
//   phase P: vmcnt(2) [g<=ghalves, else 0]; BARRIER; stage(P+3);
//            b/a ds_reads; setprio(1) 16 MFMA setprio(0).
// Invariants (hand-verified):
//  - stage(P+3) writes slot (P-1)&3 whose last reads completed before
//    phase P-1's MFMAs (compiler lgkm waits) => before every wave passed
//    this phase's barrier. Reads at P touch slots P&3,(P+1)&3 only.
//  - vmcnt(2) before the barrier leaves only the newest stage in flight,
//    so halves staged <=P-2 (the ones read at P) are landed collectively.
//  - epilogue drains 2->0 via the g<=ghalves test; prologue = stage(0..2).
// Slot swizzle unchanged: 128 superrows x 64 cols, chunk pos=(ch+sr)&7 via
// permuted per-lane GLOBAL source (LDS dest of global_load_lds is linear).
// Requires: M%256==0, B padded to gridDim.x*256 rows, K%64==0, K>=128,
// (gridDim.x*gridDim.y)%8==0, gridDim.y%4==0. C stores guarded at Nreal.
// NOTE (R2): do NOT double-buffer a/b fragments (VGPR spill -> 2x dur).
__global__ __launch_bounds__(512, 4) void gemm256_kernel(
    const unsigned short* __restrict__ A, int lda,
    const unsigned short* __restrict__ B, int ldb,
    unsigned short* __restrict__ Cout, int ldc, int K, int Nreal) {
    __shared__ __align__(16) unsigned short lds[4][8192];
    const int tid = threadIdx.x;
    const int nkt = K >> 6;
    const int ghalves = nkt << 2;

    // XCD-bijective remap (nwg%8==0) + band-of-4 bm rows per XCD chunk
    int nwg = gridDim.x * gridDim.y;
    int orig = blockIdx.y * gridDim.x + blockIdx.x;
    int q8 = nwg >> 3;
    int wgid = (orig & 7) * q8 + (orig >> 3);
    int W = gridDim.x * 4;
    int band = wgid / W, rem = wgid % W;
    int bm = band * 4 + (rem & 3), bn = rem >> 2;

    const int wave = tid >> 6, lane = tid & 63;
    const int wm = wave >> 2, wn = wave & 3;
    const int quad = lane >> 4, l15 = lane & 15;
    // fragment read addressing: element (row,c): superrow=row>>1,
    // chunk=(row&1)*4+(c>>3), stored at pos=(chunk+superrow)&7.
    const int cpos = (((l15 & 1) << 2) + quad + (l15 >> 1)) & 7;
    const int aoff = wm * 4096 + (l15 >> 1) * 64 + cpos * 8;
    const int boff = wn * 2048 + (l15 >> 1) * 64 + cpos * 8;

    // staging: per call 512 threads x 16B = 64 superrows x 8 chunks
    const int srow = tid >> 3;                 // superrow (call0)
    const int dch  = tid & 7;                  // dest chunk (linear LDS)
    const int ech  = (dch - srow) & 7;         // element chunk at this pos
    const int g_r0 = 2 * srow + (ech >> 2);    // global row within tile
    const int g_c0 = (ech & 3) * 8;            // col within 32-col k-half
    const unsigned short* A0 = A + (size_t)(bm * 256 + g_r0) * lda + g_c0;
    const unsigned short* A1 = A0 + (size_t)128 * lda;
    const unsigned short* B0 = B + (size_t)(bn * 256 + g_r0) * ldb + g_c0;
    const unsigned short* B1 = B0 + (size_t)128 * ldb;

    // half g: tile g>>2, idx g&3: 0=A-k0 1=B-k0 2=A-k1 3=B-k1; slot g&3
    auto stage = [&](int g) {
        int tg = g >> 2, idx = g & 3;
        int k0 = tg * 64 + ((idx >> 1) << 5);
        unsigned short* d = &lds[g & 3][tid * 8];
        if (idx & 1) { gload16(B0 + k0, d); gload16(B1 + k0, d + 4096); }
        else         { gload16(A0 + k0, d); gload16(A1 + k0, d + 4096); }
    };

    f32x4 acc[8][4] = {};
    // prologue: first 3 halves in flight (first phase's vmcnt+BAR lands 0,1)
    stage(0); stage(1); stage(2);

    short8 a[8], b[2];
    for (int t = 0; t < nkt; ++t) {
        #pragma unroll
        for (int ph = 0; ph < 4; ++ph) {
            const int kk = ph >> 1, nq = ph & 1;
            const unsigned short* As = lds[(4 * t + 2 * kk) & 3];
            const unsigned short* Bs = lds[(4 * t + 2 * kk + 1) & 3];
            const int g = 4 * t + 3 + ph;
            if (g <= ghalves) asm volatile("s_waitcnt vmcnt(2)");
            else              asm volatile("s_waitcnt vmcnt(0)");
            __builtin_amdgcn_s_barrier();
            if (g < ghalves) stage(g);
            b[0] = *(const short8*)&Bs[boff + (nq * 2) * 512];
            b[1] = *(const short8*)&Bs[boff + (nq * 2 + 1) * 512];
            if (nq == 0) {
                #pragma unroll
                for (int m = 0; m < 8; ++m)
                    a[m] = *(const short8*)&As[aoff + m * 512];
            }
            __builtin_amdgcn_s_setprio(1);
            #pragma unroll
            for (int m = 0; m < 8; ++m) {
                acc[m][nq * 2]     = __builtin_amdgcn_mfma_f32_16x16x32_bf16(
                    a[m], b[0], acc[m][nq * 2], 0, 0, 0);
                acc[m][nq * 2 + 1] = __builtin_amdgcn_mfma_f32_16x16x32_bf16(
                    a[m], b[1], acc[m][nq * 2 + 1], 0, 0, 0);
            }
            __builtin_amdgcn_s_setprio(0);
        }
    }

    const int rbase = bm * 256 + wm * 128 + quad * 4;
    const int cb0 = bn * 256 + wn * 64 + l15;
    #pragma unroll
    for (int m = 0; m < 8; ++m) {
        #pragma unroll
        for (int n = 0; n < 4; ++n) {
            int cb = cb0 + n * 16;
            if (cb < Nreal) {   // Nreal %16==0 -> wave-uniform predicate
                unsigned short* cp = Cout + (size_t)(rbase + m * 16) * ldc + cb;
                #pragma unroll
                for (int r = 0; r < 4; ++r)
                    cp[(size_t)r * ldc] = f2bf(acc[m][n][r]);
            }
        }
    }
}

// ---------------- GEMM: C[M,N] = A[M,K] @ B[N,K]^T  (bf16 in, fp32 acc) ----
// MODE 2: fp32 out = acc + x + P(bf16) + Qc(fp32).  (MODE 1 superseded by
// gemm256_kernel.)  LDS xor-swizzled; block order remapped in bands of 8
// bm-rows for L2 reuse (requires gridDim.y % 8 == 0).
template<int MODE>
__global__ __launch_bounds__(256) void gemm_bt_kernel(
    const unsigned short* __restrict__ A, int lda,
    const unsigned short* __restrict__ B, int ldb,
    void* __restrict__ Cout, int ldc, int K,
    const float* __restrict__ addX, const unsigned short* __restrict__ Zbuf) {
    __shared__ __align__(16) unsigned short sA[128 * 64];
    __shared__ __align__(16) unsigned short sB[128 * 64];
    int tid = threadIdx.x;
    int bid = blockIdx.y * gridDim.x + blockIdx.x;
    int W = gridDim.x * 8;
    int band = bid / W, rem = bid % W;
    int bn = rem >> 3, bm = band * 8 + (rem & 7);
    int wave = tid >> 6, lane = tid & 63;
    int wm = wave >> 1, wn = wave & 1;
    f32x4 acc[4][4] = {};
    const unsigned short* Ab = A + (size_t)(bm * 128) * lda;
    const unsigned short* Bb = B + (size_t)(bn * 128) * ldb;
    int sRow = tid >> 3;
    int srcoff = (((tid & 7) - (tid >> 3)) & 7) * 8;
    int quad = lane >> 4, l15 = lane & 15;
    for (int k0 = 0; k0 < K; k0 += 64) {
        __syncthreads();
        #pragma unroll
        for (int it = 0; it < 4; ++it) {
            int row = sRow + it * 32;
            gload16(&Ab[(size_t)row * lda + k0 + srcoff], &sA[it * 2048 + tid * 8]);
            gload16(&Bb[(size_t)row * ldb + k0 + srcoff], &sB[it * 2048 + tid * 8]);
        }
        __syncthreads();
        #pragma unroll
        for (int kk = 0; kk < 64; kk += 32) {
            short8 a[4], b[4];
            #pragma unroll
            for (int i = 0; i < 4; ++i) {
                int mr = wm * 64 + i * 16 + l15;
                a[i] = *(const short8*)&sA[mr * 64 + (((kk >> 3) + quad + mr) & 7) * 8];
                int nr = wn * 64 + i * 16 + l15;
                b[i] = *(const short8*)&sB[nr * 64 + (((kk >> 3) + quad + nr) & 7) * 8];
            }
            #pragma unroll
            for (int i = 0; i < 4; ++i)
                #pragma unroll
                for (int j = 0; j < 4; ++j)
                    acc[i][j] = __builtin_amdgcn_mfma_f32_16x16x32_bf16(
                        a[i], b[j], acc[i][j], 0, 0, 0);
        }
    }
    int rbase = bm * 128 + wm * 64 + quad * 4;
    int cbase = bn * 128 + wn * 64 + l15;
    #pragma unroll
    for (int i = 0; i < 4; ++i) {
        #pragma unroll
        for (int r = 0; r < 4; ++r) {
            int gr = rbase + i * 16 + r;
            if constexpr (MODE == 1) {
                unsigned short* crow = (unsigned short*)Cout + (size_t)gr * ldc + cbase;
                #pragma unroll
                for (int j = 0; j < 4; ++j) crow[j * 16] = f2bf(acc[i][j][r]);
            } else {
                float* crow = (float*)Cout + (size_t)gr * ldc + cbase;
                const float* xr = addX + (size_t)gr * DMODEL + cbase;
                const unsigned short* zrow = Zbuf + (size_t)gr * NBIG;
                const float* qrow = (const float*)zrow;
                #pragma unroll
                for (int j = 0; j < 4; ++j)
                    crow[j * 16] = acc[i][j][r] + xr[j * 16]
                                 + bf2f(zrow[4384 + cbase + j * 16])
                                 + qrow[cbase + j * 16];
            }
        }
    }
}

// ---- 64x64-tile GEMM (bf16 out) for the small prep GEMMs: 4x occupancy ----
// Both prep GEMMs in ONE launch via blockIdx.z (each alone only half-fills
// the 256-CU chip at 256 blocks; merged = 512 blocks).
__global__ __launch_bounds__(256) void gemm64_kernel(
    const unsigned short* __restrict__ Aa, const unsigned short* __restrict__ Ab2,
    int lda,
    const unsigned short* __restrict__ Ba, const unsigned short* __restrict__ Bb2,
    int ldb,
    unsigned short* __restrict__ Ca, unsigned short* __restrict__ Cb2,
    int ldc, int K) {
    __shared__ __align__(16) unsigned short sA[64 * 64];
    __shared__ __align__(16) unsigned short sB[64 * 64];
    int tid = threadIdx.x;
    int bn = blockIdx.x, bm = blockIdx.y;
    const unsigned short* A = blockIdx.z ? Ab2 : Aa;
    const unsigned short* B = blockIdx.z ? Bb2 : Ba;
    unsigned short* Cout    = blockIdx.z ? Cb2 : Ca;
    int wave = tid >> 6, lane = tid & 63;
    int wm = wave >> 1, wn = wave & 1;
    f32x4 acc[2][2] = {};
    const unsigned short* Ab = A + (size_t)(bm * 64) * lda;
    const unsigned short* Bb = B + (size_t)(bn * 64) * ldb;
    int sRow = tid >> 3;
    int srcoff = (((tid & 7) - (tid >> 3)) & 7) * 8;
    int quad = lane >> 4, l15 = lane & 15;
    for (int k0 = 0; k0 < K; k0 += 64) {
        __syncthreads();
        #pragma unroll
        for (int it = 0; it < 2; ++it) {
            int row = sRow + it * 32;
            gload16(&Ab[(size_t)row * lda + k0 + srcoff], &sA[it * 2048 + tid * 8]);
            gload16(&Bb[(size_t)row * ldb + k0 + srcoff], &sB[it * 2048 + tid * 8]);
        }
        __syncthreads();
        #pragma unroll
        for (int kk = 0; kk < 64; kk += 32) {
            short8 a[2], b[2];
            #pragma unroll
            for (int i = 0; i < 2; ++i) {
                int mr = wm * 32 + i * 16 + l15;
                a[i] = *(const short8*)&sA[mr * 64 + (((kk >> 3) + quad + mr) & 7) * 8];
                int nr = wn * 32 + i * 16 + l15;
                b[i] = *(const short8*)&sB[nr * 64 + (((kk >> 3) + quad + nr) & 7) * 8];
            }
            #pragma unroll
            for (int i = 0; i < 2; ++i)
                #pragma unroll
                for (int j = 0; j < 2; ++j)
                    acc[i][j] = __builtin_amdgcn_mfma_f32_16x16x32_bf16(
                        a[i], b[j], acc[i][j], 0, 0, 0);
        }
    }
    int rbase = bm * 64 + wm * 32 + quad * 4;
    int cbase = bn * 64 + wn * 32 + l15;
    #pragma unroll
    for (int i = 0; i < 2; ++i)
        #pragma unroll
        for (int r = 0; r < 4; ++r) {
            int gr = rbase + i * 16 + r;
            unsigned short* crow = Cout + (size_t)gr * ldc + cbase;
            #pragma unroll
            for (int j = 0; j < 2; ++j) crow[j * 16] = f2bf(acc[i][j][r]);
        }
}

// ---------------- conv4 (causal, depthwise) + silu ----------------
// Strip-mined: 16 tokens per block, per-thread register history (h1..h3)
// shifted along the strip -> reads each Z row ~1.19x instead of 4x
// (151 MB -> 45 MB). 9 channels/thread (9*256 = 2304).
__global__ __launch_bounds__(256) void conv_silu_kernel(
    const unsigned short* __restrict__ Z, const float* __restrict__ convW,
    const float* __restrict__ convB, unsigned short* __restrict__ xbc) {
    int blk = blockIdx.x;                  // 512 blocks: bi*256 + s
    int bi = blk >> 8, s = blk & 255;
    int t0 = s * CTOK;
    int tid = threadIdx.x;
    const size_t zbase = (size_t)(bi * SEQL) * NBIG + 2048 + tid;
    float w0[9], w1[9], w2[9], w3[9], bs[9], h1[9], h2[9], h3[9];
    #pragma unroll
    for (int k = 0; k < 9; ++k) {
        int c = tid + (k << 8);
        w0[k] = convW[c];
        w1[k] = convW[CONVD + c];
        w2[k] = convW[2 * CONVD + c];
        w3[k] = convW[3 * CONVD + c];
        bs[k] = convB[c];
        h3[k] = (t0 >= 3) ? bf2f(Z[zbase + (size_t)(t0 - 3) * NBIG + (k << 8)]) : 0.f;
        h2[k] = (t0 >= 2) ? bf2f(Z[zbase + (size_t)(t0 - 2) * NBIG + (k << 8)]) : 0.f;
        h1[k] = (t0 >= 1) ? bf2f(Z[zbase + (size_t)(t0 - 1) * NBIG + (k << 8)]) : 0.f;
    }
    for (int t = t0; t < t0 + CTOK; ++t) {
        size_t zr = zbase + (size_t)t * NBIG;
        size_t xr = (size_t)(bi * SEQL + t) * CONVD + tid;
        #pragma unroll
        for (int k = 0; k < 9; ++k) {
            float cur = bf2f(Z[zr + (k << 8)]);
            float a = bs[k] + w0[k] * h3[k] + w1[k] * h2[k]
                            + w2[k] * h1[k] + w3[k] * cur;
            h3[k] = h2[k]; h2[k] = h1[k]; h1[k] = cur;
            xbc[xr + (k << 8)] = f2bf(a / (1.0f + expf(-a)));
        }
    }
}

// ================= SSD chunked scan =================
__global__ __launch_bounds__(256, 2) void chunk_intra_kernel(
    const unsigned short* __restrict__ xbc, const unsigned short* __restrict__ Z,
    const float* __restrict__ dt_bias, const float* __restrict__ A_log,
    unsigned short* __restrict__ TS, float* __restrict__ abuf,
    unsigned short* __restrict__ ym) {
    __shared__ __align__(16) unsigned short Xt[64 * SP];
    __shared__ __align__(16) unsigned short Xw[64 * SP];
    __shared__ __align__(16) unsigned short BtM[128 * SP];
    __shared__ float dt_lds[128], dtA_lds[128], cum_lds[128], w_lds[128];
    int tid = threadIdx.x;
    int kch = blockIdx.x, bh = blockIdx.y;
    int h = bh & 31, bi = bh >> 5;
    int tok0 = bi * SEQL + kch * CHT;
    const unsigned short* xb = xbc + (size_t)tok0 * CONVD;
    if (tid < 128) {
        float v = bf2f(Z[(size_t)(tok0 + tid) * NBIG + 4352 + h]) + dt_bias[h];
        float sp = (v > 20.f) ? v : log1pf(expf(v));
        dt_lds[tid] = sp;
        dtA_lds[tid] = -sp * expf(A_log[h]);
    }
    for (int seg = tid; seg < 128 * 16; seg += 256) {
        int s = seg & 127, nb = seg >> 7;
        short8 v = *(const short8*)&xb[(size_t)s * CONVD + 2048 + nb * 8];
        #pragma unroll
        for (int j = 0; j < 8; ++j) BtM[(nb * 8 + j) * SP + s] = (unsigned short)v[j];
    }
    for (int seg = tid; seg < 128 * 8; seg += 256) {
        int s = seg & 127, pb = seg >> 7;
        short8 v = *(const short8*)&xb[(size_t)s * CONVD + h * 64 + pb * 8];
        #pragma unroll
        for (int j = 0; j < 8; ++j) Xt[(pb * 8 + j) * SP + s] = (unsigned short)v[j];
    }
    __syncthreads();
    if (tid < 128) {
        int lw = tid & 63;
        float v = dtA_lds[tid];
        #pragma unroll
        for (int off = 1; off < 64; off <<= 1) {
            float o = __shfl_up(v, off, 64);
            if (lw >= off) v += o;
        }
        cum_lds[tid] = v;
    }
    __syncthreads();
    if (tid >= 64 && tid < 128) cum_lds[tid] += cum_lds[63];
    __syncthreads();
    if (tid < 128) {
        float cT = cum_lds[127];
        w_lds[tid] = __expf(cT - cum_lds[tid]) * dt_lds[tid];
        abuf[(size_t)(bh * NCH + kch) * 128 + tid] = __expf(cum_lds[tid]);
    }
    __syncthreads();
    for (int seg = tid; seg < 64 * 16; seg += 256) {
        int pp = seg >> 4, sb = seg & 15;
        short8 v = *(const short8*)&Xt[pp * SP + sb * 8];
        short8 o;
        #pragma unroll
        for (int j = 0; j < 8; ++j)
            o[j] = (short)f2bf(bf2f((unsigned short)v[j]) * w_lds[sb * 8 + j]);
        *(short8*)&Xw[pp * SP + sb * 8] = o;
    }
    __syncthreads();
    int lane = tid & 63, wv = tid >> 6;
    int quad = lane >> 4, l15 = lane & 15;
    {
        f32x4 acc[8] = {};
        for (int kk = 0; kk < 128; kk += 32) {
            short8 a = *(const short8*)&Xw[(16 * wv + l15) * SP + kk + quad * 8];
            #pragma unroll
            for (int jn = 0; jn < 8; ++jn) {
                short8 b = *(const short8*)&BtM[(16 * jn + l15) * SP + kk + quad * 8];
                acc[jn] = __builtin_amdgcn_mfma_f32_16x16x32_bf16(a, b, acc[jn], 0, 0, 0);
            }
        }
        size_t tsbase = (size_t)(bh * NCH + kch) * 8192;
        #pragma unroll
        for (int jn = 0; jn < 8; ++jn)
            #pragma unroll
            for (int r = 0; r < 4; ++r) {
                int pp = 16 * wv + quad * 4 + r, n = 16 * jn + l15;
                TS[tsbase + pp * 128 + n] = f2bf(acc[jn][r]);
            }
    }
    __syncthreads();
    {
        f32x4 g[2][8] = {};
        for (int kk = 0; kk < 128; kk += 32) {
            int co = 2176 + kk + quad * 8;
            short8 a0 = *(const short8*)&xb[(size_t)(32 * wv + l15) * CONVD + co];
            short8 a1 = *(const short8*)&xb[(size_t)(32 * wv + 16 + l15) * CONVD + co];
            int bo = 2048 + kk + quad * 8;
            #pragma unroll
            for (int js = 0; js < 8; ++js) {
                short8 b = *(const short8*)&xb[(size_t)(16 * js + l15) * CONVD + bo];
                g[0][js] = __builtin_amdgcn_mfma_f32_16x16x32_bf16(a0, b, g[0][js], 0, 0, 0);
                g[1][js] = __builtin_amdgcn_mfma_f32_16x16x32_bf16(a1, b, g[1][js], 0, 0, 0);
            }
        }
        #pragma unroll
        for (int it = 0; it < 2; ++it)
            #pragma unroll
            for (int js = 0; js < 8; ++js) {
                int s = 16 * js + l15;
                float cs = cum_lds[s], ds = dt_lds[s];
                #pragma unroll
                for (int r = 0; r < 4; ++r) {
                    int t = 32 * wv + 16 * it + quad * 4 + r;
                    float f = (s <= t) ? __expf(cum_lds[t] - cs) * ds : 0.f;
                    BtM[t * SP + s] = f2bf(g[it][js][r] * f);
                }
            }
    }
    __syncthreads();
    {
        f32x4 y[2][4] = {};
        for (int kk = 0; kk < 128; kk += 32) {
            short8 a0 = *(const short8*)&BtM[(32 * wv + l15) * SP + kk + quad * 8];
            short8 a1 = *(const short8*)&BtM[(32 * wv + 16 + l15) * SP + kk + quad * 8];
            #pragma unroll
            for (int jp = 0; jp < 4; ++jp) {
                short8 b = *(const short8*)&Xt[(16 * jp + l15) * SP + kk + quad * 8];
                y[0][jp] = __builtin_amdgcn_mfma_f32_16x16x32_bf16(a0, b, y[0][jp], 0, 0, 0);
                y[1][jp] = __builtin_amdgcn_mfma_f32_16x16x32_bf16(a1, b, y[1][jp], 0, 0, 0);
            }
        }
        #pragma unroll
        for (int it = 0; it < 2; ++it)
            #pragma unroll
            for (int jp = 0; jp < 4; ++jp)
                #pragma unroll
                for (int r = 0; r < 4; ++r) {
                    int t = 32 * wv + 16 * it + quad * 4 + r;
                    int pp = 16 * jp + l15;
                    ym[(size_t)(tok0 + t) * DIN + h * 64 + pp] = f2bf(y[it][jp][r]);
                }
    }
}

__global__ __launch_bounds__(128) void state_recur_kernel(
    unsigned short* __restrict__ TS, const float* __restrict__ abuf) {
    int bh = blockIdx.x >> 6, p = blockIdx.x & 63, n = threadIdx.x;
    float s = 0.f;
    for (int k = 0; k < NCH; ++k) {
        size_t base = ((size_t)(bh * NCH + k) * 64 + p) * 128 + n;
        float aT = abuf[(size_t)(bh * NCH + k) * 128 + 127];
        float tv = bf2f(TS[base]);
        TS[base] = f2bf(s);
        s = fmaf(aT, s, tv);
    }
}

__global__ __launch_bounds__(256) void chunk_inter_kernel(
    const unsigned short* __restrict__ xbc, const unsigned short* __restrict__ TS,
    const float* __restrict__ abuf, const float* __restrict__ Dp,
    unsigned short* ym) {
    __shared__ float a_ld[128];
    int tid = threadIdx.x;
    int kch = blockIdx.x, bh = blockIdx.y;
    int h = bh & 31, bi = bh >> 5;
    int tok0 = bi * SEQL + kch * CHT;
    if (tid < 128) a_ld[tid] = abuf[(size_t)(bh * NCH + kch) * 128 + tid];
    __syncthreads();
    int lane = tid & 63, wv = tid >> 6;
    int quad = lane >> 4, l15 = lane & 15;
    const unsigned short* xb = xbc + (size_t)tok0 * CONVD;
    size_t tsbase = (size_t)(bh * NCH + kch) * 8192;
    int t0 = 32 * wv + l15, t1 = t0 + 16;
    float at0 = a_ld[t0], at1 = a_ld[t1];
    f32x4 y[2][4] = {};
    for (int kk = 0; kk < 128; kk += 32) {
        int co = 2176 + kk + quad * 8;
        short8 c0 = *(const short8*)&xb[(size_t)t0 * CONVD + co];
        short8 c1 = *(const short8*)&xb[(size_t)t1 * CONVD + co];
        short8 a0, a1;
        #pragma unroll
        for (int j = 0; j < 8; ++j) {
            a0[j] = (short)f2bf(bf2f((unsigned short)c0[j]) * at0);
            a1[j] = (short)f2bf(bf2f((unsigned short)c1[j]) * at1);
        }
        #pragma unroll
        for (int jp = 0; jp < 4; ++jp) {
            short8 b = *(const short8*)&TS[tsbase + (size_t)(16 * jp + l15) * 128 + kk + quad * 8];
            y[0][jp] = __builtin_amdgcn_mfma_f32_16x16x32_bf16(a0, b, y[0][jp], 0, 0, 0);
            y[1][jp] = __builtin_amdgcn_mfma_f32_16x16x32_bf16(a1, b, y[1][jp], 0, 0, 0);
        }
    }
    float Dh = Dp[h];
    #pragma unroll
    for (int it = 0; it < 2; ++it)
        #pragma unroll
        for (int jp = 0; jp < 4; ++jp)
            #pragma unroll
            for (int r = 0; r < 4; ++r) {
                int t = 32 * wv + 16 * it + quad * 4 + r;
                int pp = 16 * jp + l15;
                size_t yi = (size_t)(tok0 + t) * DIN + h * 64 + pp;
                float xv = bf2f(xb[(size_t)t * CONVD + h * 64 + pp]);
                float yv = y[it][jp][r] + bf2f(ym[yi]) + Dh * xv;
                ym[yi] = f2bf(yv);
            }
}

// ---------------- gated rmsnorm ----------------
__global__ __launch_bounds__(256) void gated_norm_kernel(
    const unsigned short* __restrict__ y,
    const unsigned short* __restrict__ Z,
    const float* __restrict__ gw, unsigned short* mamba) {
    int tok = blockIdx.x, tid = threadIdx.x;
    float vals[8];
    float ss = 0;
    #pragma unroll
    for (int i = 0; i < 8; ++i) {
        int c = tid + i * 256;
        float yv = bf2f(y[(size_t)tok * DIN + c]);
        float zv = bf2f(Z[(size_t)tok * NBIG + c]);
        float g = yv * (zv / (1.0f + expf(-zv)));
        vals[i] = g;
        ss += g * g;
    }
    #pragma unroll
    for (int off = 32; off > 0; off >>= 1) ss += __shfl_xor(ss, off, 64);
    __shared__ float sred[4];
    if ((tid & 63) == 0) sred[tid >> 6] = ss;
    __syncthreads();
    float tot = sred[0] + sred[1] + sred[2] + sred[3];
    float r = rsqrtf(tot * (1.0f / DIN) + 1e-5f);
    #pragma unroll
    for (int i = 0; i < 8; ++i) {
        int c = tid + i * 256;
        mamba[(size_t)tok * DIN + c] = f2bf(vals[i] * r * gw[c]);
    }
}

// ---------------- chunked cumsum over L of Q ----------------
__global__ void cumsum_pass1_kernel(const unsigned short* __restrict__ Z,
                                    float* __restrict__ S) {
    int cg = blockIdx.x & 3, ch = (blockIdx.x >> 2) & 31, bi = blockIdx.x >> 7;
    int c = cg * 256 + threadIdx.x;
    size_t base = (size_t)(bi * SEQL + ch * 128) * NBIG;
    float s = 0;
    for (int t = 0; t < 128; ++t)
        s += bf2f(Z[base + (size_t)t * NBIG + 5408 + c]);
    S[(bi * 32 + ch) * 1024 + c] = s;
}

__global__ void cumsum_pass2_kernel(unsigned short* __restrict__ Z,
                                    const float* __restrict__ S) {
    int cg = blockIdx.x & 3, ch = (blockIdx.x >> 2) & 31, bi = blockIdx.x >> 7;
    int c = cg * 256 + threadIdx.x;
    float run = 0;
    for (int k = 0; k < ch; ++k) run += S[(bi * 32 + k) * 1024 + c];
    size_t base = (size_t)(bi * SEQL + ch * 128) * NBIG;
    for (int t = 0; t < 128; ++t) {
        size_t row = base + (size_t)t * NBIG;
        run += bf2f(Z[row + 5408 + c]);
        ((float*)(Z + row))[c] = run;
    }
}

// ---------------- launch ----------------
extern "C" void kernel_launch(void* const* d_in, const int* in_sizes, int n_in,
                              void* d_out, int out_size, void* d_ws, size_t ws_size,
                              hipStream_t stream) {
    (void)in_sizes; (void)n_in; (void)out_size; (void)ws_size;
    const float* x        = (const float*)d_in[0];
    const float* norm_w   = (const float*)d_in[1];
    const float* in_projW = (const float*)d_in[2];
    const float* conv_W   = (const float*)d_in[3];
    const float* conv_b   = (const float*)d_in[4];
    const float* dt_bias  = (const float*)d_in[5];
    const float* A_log    = (const float*)d_in[6];
    const float* Dp       = (const float*)d_in[7];
    const float* gnorm_w  = (const float*)d_in[8];
    const float* zero_W   = (const float*)d_in[9];
    const float* one_W    = (const float*)d_in[10];
    const float* fusion_W = (const float*)d_in[11];
    float* out = (float*)d_out;

    char* p = (char*)d_ws;
    auto alloc = [&](size_t bytes) { char* r = p; p += (bytes + 255) & ~(size_t)255; return r; };
    unsigned short* Wf_t  = (unsigned short*)alloc((size_t)DMODEL * 6144 * 2);
    char* pool0 = p;
    unsigned short* xn_bf = (unsigned short*)alloc((size_t)NTOT * DMODEL * 2);
    unsigned short* zWb   = (unsigned short*)alloc((size_t)DMODEL * DIN * 2);
    unsigned short* oWb   = (unsigned short*)alloc((size_t)DMODEL * DIN * 2);
    unsigned short* Bt    = (unsigned short*)alloc((size_t)NPAD * DMODEL * 2);  // 6656 rows
    unsigned short* xbc   = (unsigned short*)pool0;  // alias over dead prep pool
    float* abuf = (float*)alloc((size_t)64 * NCH * 128 * 4);
    float* Sb   = (float*)alloc((size_t)2 * 32 * 1024 * 4);
    unsigned short* ym  = (unsigned short*)alloc((size_t)NTOT * DIN * 2);
    unsigned short* Zbf = (unsigned short*)alloc((size_t)NTOT * NBIG * 2);
    unsigned short* TS = (unsigned short*)d_out;  // 33.5MB exact fit; dead before final GEMM

    transpose_cast_kernel<<<dim3(DPROJ / 32, DMODEL / 32), dim3(32, 8), 0, stream>>>(
        in_projW, Bt, DMODEL, DPROJ);
    transpose_cast_kernel<<<dim3(DMODEL / 32, 6144 / 32), dim3(32, 8), 0, stream>>>(
        fusion_W, Wf_t, 6144, DMODEL);
    cast_bf16_kernel<<<2048, 256, 0, stream>>>(zero_W, zWb, DMODEL * DIN);
    cast_bf16_kernel<<<2048, 256, 0, stream>>>(one_W, oWb, DMODEL * DIN);
    zero_pad_kernel<<<(NPAD - NREAL) * DMODEL / 256, 256, 0, stream>>>(
        Bt + (size_t)NREAL * DMODEL, (NPAD - NREAL) * DMODEL);

    rmsnorm_cast_kernel<<<NTOT, 256, 0, stream>>>(x, norm_w, xn_bf);

    // Mzero^T, Mone^T into Bt rows [4384,6432) — both in one z=2 launch
    gemm64_kernel<<<dim3(16, 16, 2), 256, 0, stream>>>(
        Wf_t + 2048, Wf_t + 4096, 6144,
        zWb, oWb, DIN,
        Bt + (size_t)4384 * DMODEL, Bt + (size_t)5408 * DMODEL, DMODEL, DIN);

    // big projection GEMM: 256x256, 4-slot ring, 2 blocks/CU
    gemm256_kernel<<<dim3(NPAD / 256, NTOT / 256), 512, 0, stream>>>(
        xn_bf, DMODEL, Bt, DMODEL, Zbf, NBIG, DMODEL, NBIG);

    conv_silu_kernel<<<512, 256, 0, stream>>>(Zbf, conv_W, conv_b, xbc);

    chunk_intra_kernel<<<dim3(NCH, 64), 256, 0, stream>>>(
        xbc, Zbf, dt_bias, A_log, TS, abuf, ym);
    state_recur_kernel<<<64 * 64, 128, 0, stream>>>(TS, abuf);
    chunk_inter_kernel<<<dim3(NCH, 64), 256, 0, stream>>>(
        xbc, TS, abuf, Dp, ym);

    gated_norm_kernel<<<NTOT, 256, 0, stream>>>(ym, Zbf, gnorm_w, ym);

    cumsum_pass1_kernel<<<256, 256, 0, stream>>>(Zbf, Sb);
    cumsum_pass2_kernel<<<256, 256, 0, stream>>>(Zbf, Sb);

    gemm_bt_kernel<2><<<dim3(DMODEL / 128, NTOT / 128), 256, 0, stream>>>(
        ym, DIN, Wf_t, 6144, out, DMODEL, DIN, x, Zbf);
}

// Round 6
// 595.577 us; speedup vs baseline: 2.5745x; 2.5745x over previous
//
#include <hip/hip_runtime.h>
#include <hip/hip_bf16.h>
#include <stdint.h>

// ---------------- problem constants ----------------
#define BATCH   2
#define SEQL    4096
#define DMODEL  1024
#define DIN     2048          // d_inner
#define NH      32
#define HDIM    64
#define DSTATE  128
#define CONVD   2304          // d_inner + 2*d_state
#define DPROJ   4384          // 2*d_inner + 2*d_state + nheads
#define NTOT    8192          // BATCH*SEQL
#define NBIG    6528          // padded: 4384 + 1024 + 1024 = 6432 -> 6528 (/128)
#define NREAL   6432
#define NPAD    6656          // Bt rows padded to /256 for the 256-tile GEMM
#define CHT     128           // SSD chunk length
#define NCH     32            // chunks per batch-sequence (4096/128)
#define SP      136           // padded LDS row stride for scan kernels
#define CTOK    16            // conv strip length (tokens per block)
// Z (bf16) column layout: [0,2048)=z  [2048,4352)=xBC  [4352,4384)=dt
//   [4384,5408)=P (xn@Mzero)  [5408,6432)=Q (xn@Mone)
// After cumsum pass2: fp32 cumsum(Q) occupies bytes [0,4096) of each row.

typedef __attribute__((ext_vector_type(8))) short short8;
typedef __attribute__((ext_vector_type(4))) float f32x4;

__device__ __forceinline__ unsigned short f2bf(float f) {
    unsigned int u = __builtin_bit_cast(unsigned int, f);
    return (unsigned short)((u + 0x7FFFu + ((u >> 16) & 1u)) >> 16);
}
__device__ __forceinline__ float bf2f(unsigned short u) {
    unsigned int v = ((unsigned int)u) << 16;
    return __builtin_bit_cast(float, v);
}

__device__ __forceinline__ void gload16(const void* g, void* l) {
    __builtin_amdgcn_global_load_lds(
        (const __attribute__((address_space(1))) unsigned int*)g,
        (__attribute__((address_space(3))) unsigned int*)l,
        16, 0, 0);
}

// ---------------- weight prep ----------------
__global__ void transpose_cast_kernel(const float* __restrict__ in,
                                      unsigned short* __restrict__ out,
                                      int R, int C) {
    __shared__ float tile[32][33];
    int c0 = blockIdx.x * 32, r0 = blockIdx.y * 32;
    int tx = threadIdx.x, ty = threadIdx.y;
    #pragma unroll
    for (int i = ty; i < 32; i += 8)
        tile[i][tx] = in[(size_t)(r0 + i) * C + c0 + tx];
    __syncthreads();
    #pragma unroll
    for (int i = ty; i < 32; i += 8)
        out[(size_t)(c0 + i) * R + r0 + tx] = f2bf(tile[tx][i]);
}

__global__ void cast_bf16_kernel(const float* __restrict__ in,
                                 unsigned short* __restrict__ out, int n4) {
    int i = (blockIdx.x * 256 + threadIdx.x) * 4;
    if (i < n4) {
        float4 v = *(const float4*)(in + i);
        ushort4 o;
        o.x = f2bf(v.x); o.y = f2bf(v.y); o.z = f2bf(v.z); o.w = f2bf(v.w);
        *(ushort4*)(out + i) = o;
    }
}

__global__ void zero_pad_kernel(unsigned short* __restrict__ p, int n) {
    int i = blockIdx.x * 256 + threadIdx.x;
    if (i < n) p[i] = 0;
}

// ---------------- rmsnorm + cast ----------------
__global__ __launch_bounds__(256) void rmsnorm_cast_kernel(
    const float* __restrict__ x, const float* __restrict__ w,
    unsigned short* __restrict__ xn) {
    int tok = blockIdx.x, tid = threadIdx.x;
    float4 v = ((const float4*)(x + (size_t)tok * DMODEL))[tid];
    float ss = v.x*v.x + v.y*v.y + v.z*v.z + v.w*v.w;
    #pragma unroll
    for (int off = 32; off > 0; off >>= 1) ss += __shfl_xor(ss, off, 64);
    __shared__ float sred[4];
    if ((tid & 63) == 0) sred[tid >> 6] = ss;
    __syncthreads();
    float tot = sred[0] + sred[1] + sred[2] + sred[3];
    float r = rsqrtf(tot * (1.0f / DMODEL) + 1e-5f);
    float4 wv = ((const float4*)w)[tid];
    ushort4 o;
    o.x = f2bf(v.x * r * wv.x); o.y = f2bf(v.y * r * wv.y);
    o.z = f2bf(v.z * r * wv.z); o.w = f2bf(v.w * r * wv.w);
    ((ushort4*)(xn + (size_t)tok * DMODEL))[tid] = o;
}

// ================= 256x256 GEMM (bf16 out): C = A @ B^T ====================
// R6: 4-slot LDS ring (64 KB) with __launch_bounds__(512, 2).
// R5 post-mortem: (512,4) caps the allocator at 128 VGPR -> it cut to 64 and
// spilled the 128-reg accumulator to scratch (FETCH 86MB->1.7GB, WRITE
// 104MB->2.9GB, MfmaUtil 4%, 7x dur). The bound's 2nd arg caps the
// ALLOCATOR; residency is decided by ACTUAL usage. R4's body compiled to
// 100 VGPR under (512,2) — 100 <= 128 means 4 waves/SIMD = 2 blocks/CU
// become resident naturally with 64 KB LDS, no cap needed. The R5 schedule
// itself passed (absmax 1.0) — only the bound was wrong.
// Schedule (lookahead 2 halves, ONE barrier/phase):
//   phase P: vmcnt(2) [g<=ghalves, else 0]; BARRIER; stage(P+3);
//            b/a ds_reads; setprio(1) 16 MFMA setprio(0).
// Invariants (hand-verified):
//  - stage(P+3) writes slot (P-1)&3 whose last reads completed before
//    phase P-1's MFMAs (compiler lgkm waits) => before every wave passed
//    this phase's barrier. Reads at P touch slots P&3,(P+1)&3 only.
//  - vmcnt(2) before the barrier leaves only the newest stage in flight,
//    so halves staged <=P-2 (the ones read at P) are landed collectively.
//  - epilogue drains 2->0 via the g<=ghalves test; prologue = stage(0..2).
// Slot swizzle unchanged: 128 superrows x 64 cols, chunk pos=(ch+sr)&7 via
// permuted per-lane GLOBAL source (LDS dest of global_load_lds is linear).
// Requires: M%256==0, B padded to gridDim.x*256 rows, K%64==0, K>=128,
// (gridDim.x*gridDim.y)%8==0, gridDim.y%4==0. C stores guarded at Nreal.
// NOTE (R2/R5): NEVER squeeze the register budget around the 128-reg acc.
__global__ __launch_bounds__(512, 2) void gemm256_kernel(
    const unsigned short* __restrict__ A, int lda,
    const unsigned short* __restrict__ B, int ldb,
    unsigned short* __restrict__ Cout, int ldc, int K, int Nreal) {
    __shared__ __align__(16) unsigned short lds[4][8192];
    const int tid = threadIdx.x;
    const int nkt = K >> 6;
    const int ghalves = nkt << 2;

    // XCD-bijective remap (nwg%8==0) + band-of-4 bm rows per XCD chunk
    int nwg = gridDim.x * gridDim.y;
    int orig = blockIdx.y * gridDim.x + blockIdx.x;
    int q8 = nwg >> 3;
    int wgid = (orig & 7) * q8 + (orig >> 3);
    int W = gridDim.x * 4;
    int band = wgid / W, rem = wgid % W;
    int bm = band * 4 + (rem & 3), bn = rem >> 2;

    const int wave = tid >> 6, lane = tid & 63;
    const int wm = wave >> 2, wn = wave & 3;
    const int quad = lane >> 4, l15 = lane & 15;
    // fragment read addressing: element (row,c): superrow=row>>1,
    // chunk=(row&1)*4+(c>>3), stored at pos=(chunk+superrow)&7.
    const int cpos = (((l15 & 1) << 2) + quad + (l15 >> 1)) & 7;
    const int aoff = wm * 4096 + (l15 >> 1) * 64 + cpos * 8;
    const int boff = wn * 2048 + (l15 >> 1) * 64 + cpos * 8;

    // staging: per call 512 threads x 16B = 64 superrows x 8 chunks
    const int srow = tid >> 3;                 // superrow (call0)
    const int dch  = tid & 7;                  // dest chunk (linear LDS)
    const int ech  = (dch - srow) & 7;         // element chunk at this pos
    const int g_r0 = 2 * srow + (ech >> 2);    // global row within tile
    const int g_c0 = (ech & 3) * 8;            // col within 32-col k-half
    const unsigned short* A0 = A + (size_t)(bm * 256 + g_r0) * lda + g_c0;
    const unsigned short* A1 = A0 + (size_t)128 * lda;
    const unsigned short* B0 = B + (size_t)(bn * 256 + g_r0) * ldb + g_c0;
    const unsigned short* B1 = B0 + (size_t)128 * ldb;

    // half g: tile g>>2, idx g&3: 0=A-k0 1=B-k0 2=A-k1 3=B-k1; slot g&3
    auto stage = [&](int g) {
        int tg = g >> 2, idx = g & 3;
        int k0 = tg * 64 + ((idx >> 1) << 5);
        unsigned short* d = &lds[g & 3][tid * 8];
        if (idx & 1) { gload16(B0 + k0, d); gload16(B1 + k0, d + 4096); }
        else         { gload16(A0 + k0, d); gload16(A1 + k0, d + 4096); }
    };

    f32x4 acc[8][4] = {};
    // prologue: first 3 halves in flight (first phase's vmcnt+BAR lands 0,1)
    stage(0); stage(1); stage(2);

    short8 a[8], b[2];
    for (int t = 0; t < nkt; ++t) {
        #pragma unroll
        for (int ph = 0; ph < 4; ++ph) {
            const int kk = ph >> 1, nq = ph & 1;
            const unsigned short* As = lds[(4 * t + 2 * kk) & 3];
            const unsigned short* Bs = lds[(4 * t + 2 * kk + 1) & 3];
            const int g = 4 * t + 3 + ph;
            if (g <= ghalves) asm volatile("s_waitcnt vmcnt(2)");
            else              asm volatile("s_waitcnt vmcnt(0)");
            __builtin_amdgcn_s_barrier();
            if (g < ghalves) stage(g);
            b[0] = *(const short8*)&Bs[boff + (nq * 2) * 512];
            b[1] = *(const short8*)&Bs[boff + (nq * 2 + 1) * 512];
            if (nq == 0) {
                #pragma unroll
                for (int m = 0; m < 8; ++m)
                    a[m] = *(const short8*)&As[aoff + m * 512];
            }
            __builtin_amdgcn_s_setprio(1);
            #pragma unroll
            for (int m = 0; m < 8; ++m) {
                acc[m][nq * 2]     = __builtin_amdgcn_mfma_f32_16x16x32_bf16(
                    a[m], b[0], acc[m][nq * 2], 0, 0, 0);
                acc[m][nq * 2 + 1] = __builtin_amdgcn_mfma_f32_16x16x32_bf16(
                    a[m], b[1], acc[m][nq * 2 + 1], 0, 0, 0);
            }
            __builtin_amdgcn_s_setprio(0);
        }
    }

    const int rbase = bm * 256 + wm * 128 + quad * 4;
    const int cb0 = bn * 256 + wn * 64 + l15;
    #pragma unroll
    for (int m = 0; m < 8; ++m) {
        #pragma unroll
        for (int n = 0; n < 4; ++n) {
            int cb = cb0 + n * 16;
            if (cb < Nreal) {   // Nreal %16==0 -> wave-uniform predicate
                unsigned short* cp = Cout + (size_t)(rbase + m * 16) * ldc + cb;
                #pragma unroll
                for (int r = 0; r < 4; ++r)
                    cp[(size_t)r * ldc] = f2bf(acc[m][n][r]);
            }
        }
    }
}

// ---------------- GEMM: C[M,N] = A[M,K] @ B[N,K]^T  (bf16 in, fp32 acc) ----
// MODE 2: fp32 out = acc + x + P(bf16) + Qc(fp32).  (MODE 1 superseded by
// gemm256_kernel.)  LDS xor-swizzled; block order remapped in bands of 8
// bm-rows for L2 reuse (requires gridDim.y % 8 == 0).
template<int MODE>
__global__ __launch_bounds__(256) void gemm_bt_kernel(
    const unsigned short* __restrict__ A, int lda,
    const unsigned short* __restrict__ B, int ldb,
    void* __restrict__ Cout, int ldc, int K,
    const float* __restrict__ addX, const unsigned short* __restrict__ Zbuf) {
    __shared__ __align__(16) unsigned short sA[128 * 64];
    __shared__ __align__(16) unsigned short sB[128 * 64];
    int tid = threadIdx.x;
    int bid = blockIdx.y * gridDim.x + blockIdx.x;
    int W = gridDim.x * 8;
    int band = bid / W, rem = bid % W;
    int bn = rem >> 3, bm = band * 8 + (rem & 7);
    int wave = tid >> 6, lane = tid & 63;
    int wm = wave >> 1, wn = wave & 1;
    f32x4 acc[4][4] = {};
    const unsigned short* Ab = A + (size_t)(bm * 128) * lda;
    const unsigned short* Bb = B + (size_t)(bn * 128) * ldb;
    int sRow = tid >> 3;
    int srcoff = (((tid & 7) - (tid >> 3)) & 7) * 8;
    int quad = lane >> 4, l15 = lane & 15;
    for (int k0 = 0; k0 < K; k0 += 64) {
        __syncthreads();
        #pragma unroll
        for (int it = 0; it < 4; ++it) {
            int row = sRow + it * 32;
            gload16(&Ab[(size_t)row * lda + k0 + srcoff], &sA[it * 2048 + tid * 8]);
            gload16(&Bb[(size_t)row * ldb + k0 + srcoff], &sB[it * 2048 + tid * 8]);
        }
        __syncthreads();
        #pragma unroll
        for (int kk = 0; kk < 64; kk += 32) {
            short8 a[4], b[4];
            #pragma unroll
            for (int i = 0; i < 4; ++i) {
                int mr = wm * 64 + i * 16 + l15;
                a[i] = *(const short8*)&sA[mr * 64 + (((kk >> 3) + quad + mr) & 7) * 8];
                int nr = wn * 64 + i * 16 + l15;
                b[i] = *(const short8*)&sB[nr * 64 + (((kk >> 3) + quad + nr) & 7) * 8];
            }
            #pragma unroll
            for (int i = 0; i < 4; ++i)
                #pragma unroll
                for (int j = 0; j < 4; ++j)
                    acc[i][j] = __builtin_amdgcn_mfma_f32_16x16x32_bf16(
                        a[i], b[j], acc[i][j], 0, 0, 0);
        }
    }
    int rbase = bm * 128 + wm * 64 + quad * 4;
    int cbase = bn * 128 + wn * 64 + l15;
    #pragma unroll
    for (int i = 0; i < 4; ++i) {
        #pragma unroll
        for (int r = 0; r < 4; ++r) {
            int gr = rbase + i * 16 + r;
            if constexpr (MODE == 1) {
                unsigned short* crow = (unsigned short*)Cout + (size_t)gr * ldc + cbase;
                #pragma unroll
                for (int j = 0; j < 4; ++j) crow[j * 16] = f2bf(acc[i][j][r]);
            } else {
                float* crow = (float*)Cout + (size_t)gr * ldc + cbase;
                const float* xr = addX + (size_t)gr * DMODEL + cbase;
                const unsigned short* zrow = Zbuf + (size_t)gr * NBIG;
                const float* qrow = (const float*)zrow;
                #pragma unroll
                for (int j = 0; j < 4; ++j)
                    crow[j * 16] = acc[i][j][r] + xr[j * 16]
                                 + bf2f(zrow[4384 + cbase + j * 16])
                                 + qrow[cbase + j * 16];
            }
        }
    }
}

// ---- 64x64-tile GEMM (bf16 out) for the small prep GEMMs: 4x occupancy ----
// Both prep GEMMs in ONE launch via blockIdx.z (each alone only half-fills
// the 256-CU chip at 256 blocks; merged = 512 blocks).
__global__ __launch_bounds__(256) void gemm64_kernel(
    const unsigned short* __restrict__ Aa, const unsigned short* __restrict__ Ab2,
    int lda,
    const unsigned short* __restrict__ Ba, const unsigned short* __restrict__ Bb2,
    int ldb,
    unsigned short* __restrict__ Ca, unsigned short* __restrict__ Cb2,
    int ldc, int K) {
    __shared__ __align__(16) unsigned short sA[64 * 64];
    __shared__ __align__(16) unsigned short sB[64 * 64];
    int tid = threadIdx.x;
    int bn = blockIdx.x, bm = blockIdx.y;
    const unsigned short* A = blockIdx.z ? Ab2 : Aa;
    const unsigned short* B = blockIdx.z ? Bb2 : Ba;
    unsigned short* Cout    = blockIdx.z ? Cb2 : Ca;
    int wave = tid >> 6, lane = tid & 63;
    int wm = wave >> 1, wn = wave & 1;
    f32x4 acc[2][2] = {};
    const unsigned short* Ab = A + (size_t)(bm * 64) * lda;
    const unsigned short* Bb = B + (size_t)(bn * 64) * ldb;
    int sRow = tid >> 3;
    int srcoff = (((tid & 7) - (tid >> 3)) & 7) * 8;
    int quad = lane >> 4, l15 = lane & 15;
    for (int k0 = 0; k0 < K; k0 += 64) {
        __syncthreads();
        #pragma unroll
        for (int it = 0; it < 2; ++it) {
            int row = sRow + it * 32;
            gload16(&Ab[(size_t)row * lda + k0 + srcoff], &sA[it * 2048 + tid * 8]);
            gload16(&Bb[(size_t)row * ldb + k0 + srcoff], &sB[it * 2048 + tid * 8]);
        }
        __syncthreads();
        #pragma unroll
        for (int kk = 0; kk < 64; kk += 32) {
            short8 a[2], b[2];
            #pragma unroll
            for (int i = 0; i < 2; ++i) {
                int mr = wm * 32 + i * 16 + l15;
                a[i] = *(const short8*)&sA[mr * 64 + (((kk >> 3) + quad + mr) & 7) * 8];
                int nr = wn * 32 + i * 16 + l15;
                b[i] = *(const short8*)&sB[nr * 64 + (((kk >> 3) + quad + nr) & 7) * 8];
            }
            #pragma unroll
            for (int i = 0; i < 2; ++i)
                #pragma unroll
                for (int j = 0; j < 2; ++j)
                    acc[i][j] = __builtin_amdgcn_mfma_f32_16x16x32_bf16(
                        a[i], b[j], acc[i][j], 0, 0, 0);
        }
    }
    int rbase = bm * 64 + wm * 32 + quad * 4;
    int cbase = bn * 64 + wn * 32 + l15;
    #pragma unroll
    for (int i = 0; i < 2; ++i)
        #pragma unroll
        for (int r = 0; r < 4; ++r) {
            int gr = rbase + i * 16 + r;
            unsigned short* crow = Cout + (size_t)gr * ldc + cbase;
            #pragma unroll
            for (int j = 0; j < 2; ++j) crow[j * 16] = f2bf(acc[i][j][r]);
        }
}

// ---------------- conv4 (causal, depthwise) + silu ----------------
// Strip-mined: 16 tokens per block, per-thread register history (h1..h3)
// shifted along the strip -> reads each Z row ~1.19x instead of 4x
// (151 MB -> 45 MB). 9 channels/thread (9*256 = 2304).
__global__ __launch_bounds__(256) void conv_silu_kernel(
    const unsigned short* __restrict__ Z, const float* __restrict__ convW,
    const float* __restrict__ convB, unsigned short* __restrict__ xbc) {
    int blk = blockIdx.x;                  // 512 blocks: bi*256 + s
    int bi = blk >> 8, s = blk & 255;
    int t0 = s * CTOK;
    int tid = threadIdx.x;
    const size_t zbase = (size_t)(bi * SEQL) * NBIG + 2048 + tid;
    float w0[9], w1[9], w2[9], w3[9], bs[9], h1[9], h2[9], h3[9];
    #pragma unroll
    for (int k = 0; k < 9; ++k) {
        int c = tid + (k << 8);
        w0[k] = convW[c];
        w1[k] = convW[CONVD + c];
        w2[k] = convW[2 * CONVD + c];
        w3[k] = convW[3 * CONVD + c];
        bs[k] = convB[c];
        h3[k] = (t0 >= 3) ? bf2f(Z[zbase + (size_t)(t0 - 3) * NBIG + (k << 8)]) : 0.f;
        h2[k] = (t0 >= 2) ? bf2f(Z[zbase + (size_t)(t0 - 2) * NBIG + (k << 8)]) : 0.f;
        h1[k] = (t0 >= 1) ? bf2f(Z[zbase + (size_t)(t0 - 1) * NBIG + (k << 8)]) : 0.f;
    }
    for (int t = t0; t < t0 + CTOK; ++t) {
        size_t zr = zbase + (size_t)t * NBIG;
        size_t xr = (size_t)(bi * SEQL + t) * CONVD + tid;
        #pragma unroll
        for (int k = 0; k < 9; ++k) {
            float cur = bf2f(Z[zr + (k << 8)]);
            float a = bs[k] + w0[k] * h3[k] + w1[k] * h2[k]
                            + w2[k] * h1[k] + w3[k] * cur;
            h3[k] = h2[k]; h2[k] = h1[k]; h1[k] = cur;
            xbc[xr + (k << 8)] = f2bf(a / (1.0f + expf(-a)));
        }
    }
}

// ================= SSD chunked scan =================
__global__ __launch_bounds__(256, 2) void chunk_intra_kernel(
    const unsigned short* __restrict__ xbc, const unsigned short* __restrict__ Z,
    const float* __restrict__ dt_bias, const float* __restrict__ A_log,
    unsigned short* __restrict__ TS, float* __restrict__ abuf,
    unsigned short* __restrict__ ym) {
    __shared__ __align__(16) unsigned short Xt[64 * SP];
    __shared__ __align__(16) unsigned short Xw[64 * SP];
    __shared__ __align__(16) unsigned short BtM[128 * SP];
    __shared__ float dt_lds[128], dtA_lds[128], cum_lds[128], w_lds[128];
    int tid = threadIdx.x;
    int kch = blockIdx.x, bh = blockIdx.y;
    int h = bh & 31, bi = bh >> 5;
    int tok0 = bi * SEQL + kch * CHT;
    const unsigned short* xb = xbc + (size_t)tok0 * CONVD;
    if (tid < 128) {
        float v = bf2f(Z[(size_t)(tok0 + tid) * NBIG + 4352 + h]) + dt_bias[h];
        float sp = (v > 20.f) ? v : log1pf(expf(v));
        dt_lds[tid] = sp;
        dtA_lds[tid] = -sp * expf(A_log[h]);
    }
    for (int seg = tid; seg < 128 * 16; seg += 256) {
        int s = seg & 127, nb = seg >> 7;
        short8 v = *(const short8*)&xb[(size_t)s * CONVD + 2048 + nb * 8];
        #pragma unroll
        for (int j = 0; j < 8; ++j) BtM[(nb * 8 + j) * SP + s] = (unsigned short)v[j];
    }
    for (int seg = tid; seg < 128 * 8; seg += 256) {
        int s = seg & 127, pb = seg >> 7;
        short8 v = *(const short8*)&xb[(size_t)s * CONVD + h * 64 + pb * 8];
        #pragma unroll
        for (int j = 0; j < 8; ++j) Xt[(pb * 8 + j) * SP + s] = (unsigned short)v[j];
    }
    __syncthreads();
    if (tid < 128) {
        int lw = tid & 63;
        float v = dtA_lds[tid];
        #pragma unroll
        for (int off = 1; off < 64; off <<= 1) {
            float o = __shfl_up(v, off, 64);
            if (lw >= off) v += o;
        }
        cum_lds[tid] = v;
    }
    __syncthreads();
    if (tid >= 64 && tid < 128) cum_lds[tid] += cum_lds[63];
    __syncthreads();
    if (tid < 128) {
        float cT = cum_lds[127];
        w_lds[tid] = __expf(cT - cum_lds[tid]) * dt_lds[tid];
        abuf[(size_t)(bh * NCH + kch) * 128 + tid] = __expf(cum_lds[tid]);
    }
    __syncthreads();
    for (int seg = tid; seg < 64 * 16; seg += 256) {
        int pp = seg >> 4, sb = seg & 15;
        short8 v = *(const short8*)&Xt[pp * SP + sb * 8];
        short8 o;
        #pragma unroll
        for (int j = 0; j < 8; ++j)
            o[j] = (short)f2bf(bf2f((unsigned short)v[j]) * w_lds[sb * 8 + j]);
        *(short8*)&Xw[pp * SP + sb * 8] = o;
    }
    __syncthreads();
    int lane = tid & 63, wv = tid >> 6;
    int quad = lane >> 4, l15 = lane & 15;
    {
        f32x4 acc[8] = {};
        for (int kk = 0; kk < 128; kk += 32) {
            short8 a = *(const short8*)&Xw[(16 * wv + l15) * SP + kk + quad * 8];
            #pragma unroll
            for (int jn = 0; jn < 8; ++jn) {
                short8 b = *(const short8*)&BtM[(16 * jn + l15) * SP + kk + quad * 8];
                acc[jn] = __builtin_amdgcn_mfma_f32_16x16x32_bf16(a, b, acc[jn], 0, 0, 0);
            }
        }
        size_t tsbase = (size_t)(bh * NCH + kch) * 8192;
        #pragma unroll
        for (int jn = 0; jn < 8; ++jn)
            #pragma unroll
            for (int r = 0; r < 4; ++r) {
                int pp = 16 * wv + quad * 4 + r, n = 16 * jn + l15;
                TS[tsbase + pp * 128 + n] = f2bf(acc[jn][r]);
            }
    }
    __syncthreads();
    {
        f32x4 g[2][8] = {};
        for (int kk = 0; kk < 128; kk += 32) {
            int co = 2176 + kk + quad * 8;
            short8 a0 = *(const short8*)&xb[(size_t)(32 * wv + l15) * CONVD + co];
            short8 a1 = *(const short8*)&xb[(size_t)(32 * wv + 16 + l15) * CONVD + co];
            int bo = 2048 + kk + quad * 8;
            #pragma unroll
            for (int js = 0; js < 8; ++js) {
                short8 b = *(const short8*)&xb[(size_t)(16 * js + l15) * CONVD + bo];
                g[0][js] = __builtin_amdgcn_mfma_f32_16x16x32_bf16(a0, b, g[0][js], 0, 0, 0);
                g[1][js] = __builtin_amdgcn_mfma_f32_16x16x32_bf16(a1, b, g[1][js], 0, 0, 0);
            }
        }
        #pragma unroll
        for (int it = 0; it < 2; ++it)
            #pragma unroll
            for (int js = 0; js < 8; ++js) {
                int s = 16 * js + l15;
                float cs = cum_lds[s], ds = dt_lds[s];
                #pragma unroll
                for (int r = 0; r < 4; ++r) {
                    int t = 32 * wv + 16 * it + quad * 4 + r;
                    float f = (s <= t) ? __expf(cum_lds[t] - cs) * ds : 0.f;
                    BtM[t * SP + s] = f2bf(g[it][js][r] * f);
                }
            }
    }
    __syncthreads();
    {
        f32x4 y[2][4] = {};
        for (int kk = 0; kk < 128; kk += 32) {
            short8 a0 = *(const short8*)&BtM[(32 * wv + l15) * SP + kk + quad * 8];
            short8 a1 = *(const short8*)&BtM[(32 * wv + 16 + l15) * SP + kk + quad * 8];
            #pragma unroll
            for (int jp = 0; jp < 4; ++jp) {
                short8 b = *(const short8*)&Xt[(16 * jp + l15) * SP + kk + quad * 8];
                y[0][jp] = __builtin_amdgcn_mfma_f32_16x16x32_bf16(a0, b, y[0][jp], 0, 0, 0);
                y[1][jp] = __builtin_amdgcn_mfma_f32_16x16x32_bf16(a1, b, y[1][jp], 0, 0, 0);
            }
        }
        #pragma unroll
        for (int it = 0; it < 2; ++it)
            #pragma unroll
            for (int jp = 0; jp < 4; ++jp)
                #pragma unroll
                for (int r = 0; r < 4; ++r) {
                    int t = 32 * wv + 16 * it + quad * 4 + r;
                    int pp = 16 * jp + l15;
                    ym[(size_t)(tok0 + t) * DIN + h * 64 + pp] = f2bf(y[it][jp][r]);
                }
    }
}

__global__ __launch_bounds__(128) void state_recur_kernel(
    unsigned short* __restrict__ TS, const float* __restrict__ abuf) {
    int bh = blockIdx.x >> 6, p = blockIdx.x & 63, n = threadIdx.x;
    float s = 0.f;
    for (int k = 0; k < NCH; ++k) {
        size_t base = ((size_t)(bh * NCH + k) * 64 + p) * 128 + n;
        float aT = abuf[(size_t)(bh * NCH + k) * 128 + 127];
        float tv = bf2f(TS[base]);
        TS[base] = f2bf(s);
        s = fmaf(aT, s, tv);
    }
}

__global__ __launch_bounds__(256) void chunk_inter_kernel(
    const unsigned short* __restrict__ xbc, const unsigned short* __restrict__ TS,
    const float* __restrict__ abuf, const float* __restrict__ Dp,
    unsigned short* ym) {
    __shared__ float a_ld[128];
    int tid = threadIdx.x;
    int kch = blockIdx.x, bh = blockIdx.y;
    int h = bh & 31, bi = bh >> 5;
    int tok0 = bi * SEQL + kch * CHT;
    if (tid < 128) a_ld[tid] = abuf[(size_t)(bh * NCH + kch) * 128 + tid];
    __syncthreads();
    int lane = tid & 63, wv = tid >> 6;
    int quad = lane >> 4, l15 = lane & 15;
    const unsigned short* xb = xbc + (size_t)tok0 * CONVD;
    size_t tsbase = (size_t)(bh * NCH + kch) * 8192;
    int t0 = 32 * wv + l15, t1 = t0 + 16;
    float at0 = a_ld[t0], at1 = a_ld[t1];
    f32x4 y[2][4] = {};
    for (int kk = 0; kk < 128; kk += 32) {
        int co = 2176 + kk + quad * 8;
        short8 c0 = *(const short8*)&xb[(size_t)t0 * CONVD + co];
        short8 c1 = *(const short8*)&xb[(size_t)t1 * CONVD + co];
        short8 a0, a1;
        #pragma unroll
        for (int j = 0; j < 8; ++j) {
            a0[j] = (short)f2bf(bf2f((unsigned short)c0[j]) * at0);
            a1[j] = (short)f2bf(bf2f((unsigned short)c1[j]) * at1);
        }
        #pragma unroll
        for (int jp = 0; jp < 4; ++jp) {
            short8 b = *(const short8*)&TS[tsbase + (size_t)(16 * jp + l15) * 128 + kk + quad * 8];
            y[0][jp] = __builtin_amdgcn_mfma_f32_16x16x32_bf16(a0, b, y[0][jp], 0, 0, 0);
            y[1][jp] = __builtin_amdgcn_mfma_f32_16x16x32_bf16(a1, b, y[1][jp], 0, 0, 0);
        }
    }
    float Dh = Dp[h];
    #pragma unroll
    for (int it = 0; it < 2; ++it)
        #pragma unroll
        for (int jp = 0; jp < 4; ++jp)
            #pragma unroll
            for (int r = 0; r < 4; ++r) {
                int t = 32 * wv + 16 * it + quad * 4 + r;
                int pp = 16 * jp + l15;
                size_t yi = (size_t)(tok0 + t) * DIN + h * 64 + pp;
                float xv = bf2f(xb[(size_t)t * CONVD + h * 64 + pp]);
                float yv = y[it][jp][r] + bf2f(ym[yi]) + Dh * xv;
                ym[yi] = f2bf(yv);
            }
}

// ---------------- gated rmsnorm ----------------
__global__ __launch_bounds__(256) void gated_norm_kernel(
    const unsigned short* __restrict__ y,
    const unsigned short* __restrict__ Z,
    const float* __restrict__ gw, unsigned short* mamba) {
    int tok = blockIdx.x, tid = threadIdx.x;
    float vals[8];
    float ss = 0;
    #pragma unroll
    for (int i = 0; i < 8; ++i) {
        int c = tid + i * 256;
        float yv = bf2f(y[(size_t)tok * DIN + c]);
        float zv = bf2f(Z[(size_t)tok * NBIG + c]);
        float g = yv * (zv / (1.0f + expf(-zv)));
        vals[i] = g;
        ss += g * g;
    }
    #pragma unroll
    for (int off = 32; off > 0; off >>= 1) ss += __shfl_xor(ss, off, 64);
    __shared__ float sred[4];
    if ((tid & 63) == 0) sred[tid >> 6] = ss;
    __syncthreads();
    float tot = sred[0] + sred[1] + sred[2] + sred[3];
    float r = rsqrtf(tot * (1.0f / DIN) + 1e-5f);
    #pragma unroll
    for (int i = 0; i < 8; ++i) {
        int c = tid + i * 256;
        mamba[(size_t)tok * DIN + c] = f2bf(vals[i] * r * gw[c]);
    }
}

// ---------------- chunked cumsum over L of Q ----------------
__global__ void cumsum_pass1_kernel(const unsigned short* __restrict__ Z,
                                    float* __restrict__ S) {
    int cg = blockIdx.x & 3, ch = (blockIdx.x >> 2) & 31, bi = blockIdx.x >> 7;
    int c = cg * 256 + threadIdx.x;
    size_t base = (size_t)(bi * SEQL + ch * 128) * NBIG;
    float s = 0;
    for (int t = 0; t < 128; ++t)
        s += bf2f(Z[base + (size_t)t * NBIG + 5408 + c]);
    S[(bi * 32 + ch) * 1024 + c] = s;
}

__global__ void cumsum_pass2_kernel(unsigned short* __restrict__ Z,
                                    const float* __restrict__ S) {
    int cg = blockIdx.x & 3, ch = (blockIdx.x >> 2) & 31, bi = blockIdx.x >> 7;
    int c = cg * 256 + threadIdx.x;
    float run = 0;
    for (int k = 0; k < ch; ++k) run += S[(bi * 32 + k) * 1024 + c];
    size_t base = (size_t)(bi * SEQL + ch * 128) * NBIG;
    for (int t = 0; t < 128; ++t) {
        size_t row = base + (size_t)t * NBIG;
        run += bf2f(Z[row + 5408 + c]);
        ((float*)(Z + row))[c] = run;
    }
}

// ---------------- launch ----------------
extern "C" void kernel_launch(void* const* d_in, const int* in_sizes, int n_in,
                              void* d_out, int out_size, void* d_ws, size_t ws_size,
                              hipStream_t stream) {
    (void)in_sizes; (void)n_in; (void)out_size; (void)ws_size;
    const float* x        = (const float*)d_in[0];
    const float* norm_w   = (const float*)d_in[1];
    const float* in_projW = (const float*)d_in[2];
    const float* conv_W   = (const float*)d_in[3];
    const float* conv_b   = (const float*)d_in[4];
    const float* dt_bias  = (const float*)d_in[5];
    const float* A_log    = (const float*)d_in[6];
    const float* Dp       = (const float*)d_in[7];
    const float* gnorm_w  = (const float*)d_in[8];
    const float* zero_W   = (const float*)d_in[9];
    const float* one_W    = (const float*)d_in[10];
    const float* fusion_W = (const float*)d_in[11];
    float* out = (float*)d_out;

    char* p = (char*)d_ws;
    auto alloc = [&](size_t bytes) { char* r = p; p += (bytes + 255) & ~(size_t)255; return r; };
    unsigned short* Wf_t  = (unsigned short*)alloc((size_t)DMODEL * 6144 * 2);
    char* pool0 = p;
    unsigned short* xn_bf = (unsigned short*)alloc((size_t)NTOT * DMODEL * 2);
    unsigned short* zWb   = (unsigned short*)alloc((size_t)DMODEL * DIN * 2);
    unsigned short* oWb   = (unsigned short*)alloc((size_t)DMODEL * DIN * 2);
    unsigned short* Bt    = (unsigned short*)alloc((size_t)NPAD * DMODEL * 2);  // 6656 rows
    unsigned short* xbc   = (unsigned short*)pool0;  // alias over dead prep pool
    float* abuf = (float*)alloc((size_t)64 * NCH * 128 * 4);
    float* Sb   = (float*)alloc((size_t)2 * 32 * 1024 * 4);
    unsigned short* ym  = (unsigned short*)alloc((size_t)NTOT * DIN * 2);
    unsigned short* Zbf = (unsigned short*)alloc((size_t)NTOT * NBIG * 2);
    unsigned short* TS = (unsigned short*)d_out;  // 33.5MB exact fit; dead before final GEMM

    transpose_cast_kernel<<<dim3(DPROJ / 32, DMODEL / 32), dim3(32, 8), 0, stream>>>(
        in_projW, Bt, DMODEL, DPROJ);
    transpose_cast_kernel<<<dim3(DMODEL / 32, 6144 / 32), dim3(32, 8), 0, stream>>>(
        fusion_W, Wf_t, 6144, DMODEL);
    cast_bf16_kernel<<<2048, 256, 0, stream>>>(zero_W, zWb, DMODEL * DIN);
    cast_bf16_kernel<<<2048, 256, 0, stream>>>(one_W, oWb, DMODEL * DIN);
    zero_pad_kernel<<<(NPAD - NREAL) * DMODEL / 256, 256, 0, stream>>>(
        Bt + (size_t)NREAL * DMODEL, (NPAD - NREAL) * DMODEL);

    rmsnorm_cast_kernel<<<NTOT, 256, 0, stream>>>(x, norm_w, xn_bf);

    // Mzero^T, Mone^T into Bt rows [4384,6432) — both in one z=2 launch
    gemm64_kernel<<<dim3(16, 16, 2), 256, 0, stream>>>(
        Wf_t + 2048, Wf_t + 4096, 6144,
        zWb, oWb, DIN,
        Bt + (size_t)4384 * DMODEL, Bt + (size_t)5408 * DMODEL, DMODEL, DIN);

    // big projection GEMM: 256x256, 4-slot ring, (512,2) -> 2 blocks/CU
    // if the allocator lands <=128 VGPR (R4 body: 100)
    gemm256_kernel<<<dim3(NPAD / 256, NTOT / 256), 512, 0, stream>>>(
        xn_bf, DMODEL, Bt, DMODEL, Zbf, NBIG, DMODEL, NBIG);

    conv_silu_kernel<<<512, 256, 0, stream>>>(Zbf, conv_W, conv_b, xbc);

    chunk_intra_kernel<<<dim3(NCH, 64), 256, 0, stream>>>(
        xbc, Zbf, dt_bias, A_log, TS, abuf, ym);
    state_recur_kernel<<<64 * 64, 128, 0, stream>>>(TS, abuf);
    chunk_inter_kernel<<<dim3(NCH, 64), 256, 0, stream>>>(
        xbc, TS, abuf, Dp, ym);

    gated_norm_kernel<<<NTOT, 256, 0, stream>>>(ym, Zbf, gnorm_w, ym);

    cumsum_pass1_kernel<<<256, 256, 0, stream>>>(Zbf, Sb);
    cumsum_pass2_kernel<<<256, 256, 0, stream>>>(Zbf, Sb);

    gemm_bt_kernel<2><<<dim3(DMODEL / 128, NTOT / 128), 256, 0, stream>>>(
        ym, DIN, Wf_t, 6144, out, DMODEL, DIN, x, Zbf);
}

// Round 7
// 576.949 us; speedup vs baseline: 2.6576x; 1.0323x over previous
//
#include <hip/hip_runtime.h>
#include <hip/hip_bf16.h>
#include <stdint.h>

// ---------------- problem constants ----------------
#define BATCH   2
#define SEQL    4096
#define DMODEL  1024
#define DIN     2048          // d_inner
#define NH      32
#define HDIM    64
#define DSTATE  128
#define CONVD   2304          // d_inner + 2*d_state
#define DPROJ   4384          // 2*d_inner + 2*d_state + nheads
#define NTOT    8192          // BATCH*SEQL
#define NBIG    6528          // padded: 4384 + 1024 + 1024 = 6432 -> 6528 (/128)
#define NREAL   6432
#define NPAD    6656          // Bt rows padded to /256 for the 256-tile GEMM
#define CHT     128           // SSD chunk length
#define NCH     32            // chunks per batch-sequence (4096/128)
#define SP      136           // padded LDS row stride for scan kernels
#define CTOK    16            // conv strip length (tokens per block)
// Z (bf16) column layout: [0,2048)=z  [2048,4352)=xBC  [4352,4384)=dt
//   [4384,5408)=P (xn@Mzero)  [5408,6432)=Q (xn@Mone)
// After cumsum pass2: fp32 cumsum(Q) occupies bytes [0,4096) of each row.

typedef __attribute__((ext_vector_type(8))) short short8;
typedef __attribute__((ext_vector_type(4))) float f32x4;

__device__ __forceinline__ unsigned short f2bf(float f) {
    unsigned int u = __builtin_bit_cast(unsigned int, f);
    return (unsigned short)((u + 0x7FFFu + ((u >> 16) & 1u)) >> 16);
}
__device__ __forceinline__ float bf2f(unsigned short u) {
    unsigned int v = ((unsigned int)u) << 16;
    return __builtin_bit_cast(float, v);
}

__device__ __forceinline__ void gload16(const void* g, void* l) {
    __builtin_amdgcn_global_load_lds(
        (const __attribute__((address_space(1))) unsigned int*)g,
        (__attribute__((address_space(3))) unsigned int*)l,
        16, 0, 0);
}

// ---------------- weight prep ----------------
__global__ void transpose_cast_kernel(const float* __restrict__ in,
                                      unsigned short* __restrict__ out,
                                      int R, int C) {
    __shared__ float tile[32][33];
    int c0 = blockIdx.x * 32, r0 = blockIdx.y * 32;
    int tx = threadIdx.x, ty = threadIdx.y;
    #pragma unroll
    for (int i = ty; i < 32; i += 8)
        tile[i][tx] = in[(size_t)(r0 + i) * C + c0 + tx];
    __syncthreads();
    #pragma unroll
    for (int i = ty; i < 32; i += 8)
        out[(size_t)(c0 + i) * R + r0 + tx] = f2bf(tile[tx][i]);
}

__global__ void cast_bf16_kernel(const float* __restrict__ in,
                                 unsigned short* __restrict__ out, int n4) {
    int i = (blockIdx.x * 256 + threadIdx.x) * 4;
    if (i < n4) {
        float4 v = *(const float4*)(in + i);
        ushort4 o;
        o.x = f2bf(v.x); o.y = f2bf(v.y); o.z = f2bf(v.z); o.w = f2bf(v.w);
        *(ushort4*)(out + i) = o;
    }
}

__global__ void zero_pad_kernel(unsigned short* __restrict__ p, int n) {
    int i = blockIdx.x * 256 + threadIdx.x;
    if (i < n) p[i] = 0;
}

// ---------------- rmsnorm + cast ----------------
__global__ __launch_bounds__(256) void rmsnorm_cast_kernel(
    const float* __restrict__ x, const float* __restrict__ w,
    unsigned short* __restrict__ xn) {
    int tok = blockIdx.x, tid = threadIdx.x;
    float4 v = ((const float4*)(x + (size_t)tok * DMODEL))[tid];
    float ss = v.x*v.x + v.y*v.y + v.z*v.z + v.w*v.w;
    #pragma unroll
    for (int off = 32; off > 0; off >>= 1) ss += __shfl_xor(ss, off, 64);
    __shared__ float sred[4];
    if ((tid & 63) == 0) sred[tid >> 6] = ss;
    __syncthreads();
    float tot = sred[0] + sred[1] + sred[2] + sred[3];
    float r = rsqrtf(tot * (1.0f / DMODEL) + 1e-5f);
    float4 wv = ((const float4*)w)[tid];
    ushort4 o;
    o.x = f2bf(v.x * r * wv.x); o.y = f2bf(v.y * r * wv.y);
    o.z = f2bf(v.z * r * wv.z); o.w = f2bf(v.w * r * wv.w);
    ((ushort4*)(xn + (size_t)tok * DMODEL))[tid] = o;
}

// ================= 256x256 8-phase GEMM (bf16 out): C = A @ B^T ============
// R7: reverted to the R1-exact schedule — best measured of the family
// (R1=142.5, R3/R4 reorder=152, R6 4-slot=158; run variance ±5%).
// R6 post-mortem: VGPR_Count excludes the AGPR accumulator; unified file
// usage is ~120 VGPR + 128 AGPR ≈ 248/wave -> 2 waves/SIMD -> 1 block/CU
// ALWAYS with a 128-reg acc. Two 256-tile blocks/CU is register-impossible;
// the 4-slot/64KB variant bought nothing and lost the deeper prefetch ring.
// Structure: 8 waves (2M x 4N), BK=64 in two 32-col K-halves; LDS = 8 x
// 16KB slots streamed mod 8 (half g -> slot g&7); staging runs 7 halves
// ahead, counted vmcnt(6) once per K-tile (0 only before the final tile).
// Slot layout: 128 superrows (row pairs) x 64 cols, chunk swizzle
// pos=(ch+sr)&7 via permuted per-lane GLOBAL source (LDS dest linear).
// Per phase: {10|2} ds_read_b128 -> stage issue -> BAR -> lgkmcnt(0) ->
// setprio(1) 16 MFMA setprio(0) -> [vmcnt@ph3] -> BAR.
// Requires: M%256==0, B padded to gridDim.x*256 rows, K%64==0, K>=128,
// (gridDim.x*gridDim.y)%8==0, gridDim.y%4==0. C stores guarded at Nreal.
// NOTE (R2/R5): NEVER squeeze the register budget around the 128-reg acc
// (fragment double-buffering or launch_bounds min-waves>2 -> scratch spill).
__global__ __launch_bounds__(512, 2) void gemm256_kernel(
    const unsigned short* __restrict__ A, int lda,
    const unsigned short* __restrict__ B, int ldb,
    unsigned short* __restrict__ Cout, int ldc, int K, int Nreal) {
    __shared__ __align__(16) unsigned short lds[8][8192];
    const int tid = threadIdx.x;
    const int nkt = K >> 6;
    const int ghalves = nkt << 2;

    // XCD-bijective remap (nwg%8==0) + band-of-4 bm rows per XCD chunk
    int nwg = gridDim.x * gridDim.y;
    int orig = blockIdx.y * gridDim.x + blockIdx.x;
    int q8 = nwg >> 3;
    int wgid = (orig & 7) * q8 + (orig >> 3);
    int W = gridDim.x * 4;
    int band = wgid / W, rem = wgid % W;
    int bm = band * 4 + (rem & 3), bn = rem >> 2;

    const int wave = tid >> 6, lane = tid & 63;
    const int wm = wave >> 2, wn = wave & 3;
    const int quad = lane >> 4, l15 = lane & 15;
    // fragment read addressing: element (row,c): superrow=row>>1,
    // chunk=(row&1)*4+(c>>3), stored at pos=(chunk+superrow)&7.
    const int cpos = (((l15 & 1) << 2) + quad + (l15 >> 1)) & 7;
    const int aoff = wm * 4096 + (l15 >> 1) * 64 + cpos * 8;
    const int boff = wn * 2048 + (l15 >> 1) * 64 + cpos * 8;

    // staging: per call 512 threads x 16B = 64 superrows x 8 chunks
    const int srow = tid >> 3;                 // superrow (call0)
    const int dch  = tid & 7;                  // dest chunk (linear LDS)
    const int ech  = (dch - srow) & 7;         // element chunk at this pos
    const int g_r0 = 2 * srow + (ech >> 2);    // global row within tile
    const int g_c0 = (ech & 3) * 8;            // col within 32-col k-half
    const unsigned short* A0 = A + (size_t)(bm * 256 + g_r0) * lda + g_c0;
    const unsigned short* A1 = A0 + (size_t)128 * lda;
    const unsigned short* B0 = B + (size_t)(bn * 256 + g_r0) * ldb + g_c0;
    const unsigned short* B1 = B0 + (size_t)128 * ldb;

    // half g: tile g>>2, idx g&3: 0=A-k0 1=B-k0 2=A-k1 3=B-k1; slot g&7
    auto stage = [&](int g) {
        int tg = g >> 2, idx = g & 3;
        int k0 = tg * 64 + ((idx >> 1) << 5);
        unsigned short* d = &lds[g & 7][tid * 8];
        if (idx & 1) { gload16(B0 + k0, d); gload16(B1 + k0, d + 4096); }
        else         { gload16(A0 + k0, d); gload16(A1 + k0, d + 4096); }
    };

    f32x4 acc[8][4] = {};
    // prologue: tile0 fully + 3 halves of tile1 in flight (nkt>=2)
    stage(0); stage(1); stage(2); stage(3);
    asm volatile("s_waitcnt vmcnt(4)");
    stage(4); stage(5); stage(6);
    asm volatile("s_waitcnt vmcnt(6)");   // tile 0 resident
    __builtin_amdgcn_s_barrier();

    short8 a[8], b[2];
    for (int t = 0; t < nkt; ++t) {
        #pragma unroll
        for (int ph = 0; ph < 4; ++ph) {
            const int kk = ph >> 1, nq = ph & 1;
            const unsigned short* As = lds[(4 * t + 2 * kk) & 7];
            const unsigned short* Bs = lds[(4 * t + 2 * kk + 1) & 7];
            if (nq == 0) {
                #pragma unroll
                for (int m = 0; m < 8; ++m)
                    a[m] = *(const short8*)&As[aoff + m * 512];
            }
            b[0] = *(const short8*)&Bs[boff + (nq * 2) * 512];
            b[1] = *(const short8*)&Bs[boff + (nq * 2 + 1) * 512];
            int g = 4 * t + 7 + ph;
            if (g < ghalves) stage(g);
            __builtin_amdgcn_s_barrier();
            asm volatile("s_waitcnt lgkmcnt(0)");
            __builtin_amdgcn_s_setprio(1);
            #pragma unroll
            for (int m = 0; m < 8; ++m) {
                acc[m][nq * 2]     = __builtin_amdgcn_mfma_f32_16x16x32_bf16(
                    a[m], b[0], acc[m][nq * 2], 0, 0, 0);
                acc[m][nq * 2 + 1] = __builtin_amdgcn_mfma_f32_16x16x32_bf16(
                    a[m], b[1], acc[m][nq * 2 + 1], 0, 0, 0);
            }
            __builtin_amdgcn_s_setprio(0);
            if (ph == 3) {
                if (t == nkt - 2) asm volatile("s_waitcnt vmcnt(0)");
                else              asm volatile("s_waitcnt vmcnt(6)");
            }
            __builtin_amdgcn_s_barrier();
        }
    }

    const int rbase = bm * 256 + wm * 128 + quad * 4;
    const int cb0 = bn * 256 + wn * 64 + l15;
    #pragma unroll
    for (int m = 0; m < 8; ++m) {
        #pragma unroll
        for (int n = 0; n < 4; ++n) {
            int cb = cb0 + n * 16;
            if (cb < Nreal) {   // Nreal %16==0 -> wave-uniform predicate
                unsigned short* cp = Cout + (size_t)(rbase + m * 16) * ldc + cb;
                #pragma unroll
                for (int r = 0; r < 4; ++r)
                    cp[(size_t)r * ldc] = f2bf(acc[m][n][r]);
            }
        }
    }
}

// ---------------- GEMM: C[M,N] = A[M,K] @ B[N,K]^T  (bf16 in, fp32 acc) ----
// MODE 2: fp32 out = acc + x + P(bf16) + Qc(fp32).  (MODE 1 superseded by
// gemm256_kernel.)  LDS xor-swizzled; block order remapped in bands of 8
// bm-rows for L2 reuse (requires gridDim.y % 8 == 0).
template<int MODE>
__global__ __launch_bounds__(256) void gemm_bt_kernel(
    const unsigned short* __restrict__ A, int lda,
    const unsigned short* __restrict__ B, int ldb,
    void* __restrict__ Cout, int ldc, int K,
    const float* __restrict__ addX, const unsigned short* __restrict__ Zbuf) {
    __shared__ __align__(16) unsigned short sA[128 * 64];
    __shared__ __align__(16) unsigned short sB[128 * 64];
    int tid = threadIdx.x;
    int bid = blockIdx.y * gridDim.x + blockIdx.x;
    int W = gridDim.x * 8;
    int band = bid / W, rem = bid % W;
    int bn = rem >> 3, bm = band * 8 + (rem & 7);
    int wave = tid >> 6, lane = tid & 63;
    int wm = wave >> 1, wn = wave & 1;
    f32x4 acc[4][4] = {};
    const unsigned short* Ab = A + (size_t)(bm * 128) * lda;
    const unsigned short* Bb = B + (size_t)(bn * 128) * ldb;
    int sRow = tid >> 3;
    int srcoff = (((tid & 7) - (tid >> 3)) & 7) * 8;
    int quad = lane >> 4, l15 = lane & 15;
    for (int k0 = 0; k0 < K; k0 += 64) {
        __syncthreads();
        #pragma unroll
        for (int it = 0; it < 4; ++it) {
            int row = sRow + it * 32;
            gload16(&Ab[(size_t)row * lda + k0 + srcoff], &sA[it * 2048 + tid * 8]);
            gload16(&Bb[(size_t)row * ldb + k0 + srcoff], &sB[it * 2048 + tid * 8]);
        }
        __syncthreads();
        #pragma unroll
        for (int kk = 0; kk < 64; kk += 32) {
            short8 a[4], b[4];
            #pragma unroll
            for (int i = 0; i < 4; ++i) {
                int mr = wm * 64 + i * 16 + l15;
                a[i] = *(const short8*)&sA[mr * 64 + (((kk >> 3) + quad + mr) & 7) * 8];
                int nr = wn * 64 + i * 16 + l15;
                b[i] = *(const short8*)&sB[nr * 64 + (((kk >> 3) + quad + nr) & 7) * 8];
            }
            #pragma unroll
            for (int i = 0; i < 4; ++i)
                #pragma unroll
                for (int j = 0; j < 4; ++j)
                    acc[i][j] = __builtin_amdgcn_mfma_f32_16x16x32_bf16(
                        a[i], b[j], acc[i][j], 0, 0, 0);
        }
    }
    int rbase = bm * 128 + wm * 64 + quad * 4;
    int cbase = bn * 128 + wn * 64 + l15;
    #pragma unroll
    for (int i = 0; i < 4; ++i) {
        #pragma unroll
        for (int r = 0; r < 4; ++r) {
            int gr = rbase + i * 16 + r;
            if constexpr (MODE == 1) {
                unsigned short* crow = (unsigned short*)Cout + (size_t)gr * ldc + cbase;
                #pragma unroll
                for (int j = 0; j < 4; ++j) crow[j * 16] = f2bf(acc[i][j][r]);
            } else {
                float* crow = (float*)Cout + (size_t)gr * ldc + cbase;
                const float* xr = addX + (size_t)gr * DMODEL + cbase;
                const unsigned short* zrow = Zbuf + (size_t)gr * NBIG;
                const float* qrow = (const float*)zrow;
                #pragma unroll
                for (int j = 0; j < 4; ++j)
                    crow[j * 16] = acc[i][j][r] + xr[j * 16]
                                 + bf2f(zrow[4384 + cbase + j * 16])
                                 + qrow[cbase + j * 16];
            }
        }
    }
}

// ---- 64x64-tile GEMM (bf16 out) for the small prep GEMMs: 4x occupancy ----
// Both prep GEMMs in ONE launch via blockIdx.z (each alone only half-fills
// the 256-CU chip at 256 blocks; merged = 512 blocks).
__global__ __launch_bounds__(256) void gemm64_kernel(
    const unsigned short* __restrict__ Aa, const unsigned short* __restrict__ Ab2,
    int lda,
    const unsigned short* __restrict__ Ba, const unsigned short* __restrict__ Bb2,
    int ldb,
    unsigned short* __restrict__ Ca, unsigned short* __restrict__ Cb2,
    int ldc, int K) {
    __shared__ __align__(16) unsigned short sA[64 * 64];
    __shared__ __align__(16) unsigned short sB[64 * 64];
    int tid = threadIdx.x;
    int bn = blockIdx.x, bm = blockIdx.y;
    const unsigned short* A = blockIdx.z ? Ab2 : Aa;
    const unsigned short* B = blockIdx.z ? Bb2 : Ba;
    unsigned short* Cout    = blockIdx.z ? Cb2 : Ca;
    int wave = tid >> 6, lane = tid & 63;
    int wm = wave >> 1, wn = wave & 1;
    f32x4 acc[2][2] = {};
    const unsigned short* Ab = A + (size_t)(bm * 64) * lda;
    const unsigned short* Bb = B + (size_t)(bn * 64) * ldb;
    int sRow = tid >> 3;
    int srcoff = (((tid & 7) - (tid >> 3)) & 7) * 8;
    int quad = lane >> 4, l15 = lane & 15;
    for (int k0 = 0; k0 < K; k0 += 64) {
        __syncthreads();
        #pragma unroll
        for (int it = 0; it < 2; ++it) {
            int row = sRow + it * 32;
            gload16(&Ab[(size_t)row * lda + k0 + srcoff], &sA[it * 2048 + tid * 8]);
            gload16(&Bb[(size_t)row * ldb + k0 + srcoff], &sB[it * 2048 + tid * 8]);
        }
        __syncthreads();
        #pragma unroll
        for (int kk = 0; kk < 64; kk += 32) {
            short8 a[2], b[2];
            #pragma unroll
            for (int i = 0; i < 2; ++i) {
                int mr = wm * 32 + i * 16 + l15;
                a[i] = *(const short8*)&sA[mr * 64 + (((kk >> 3) + quad + mr) & 7) * 8];
                int nr = wn * 32 + i * 16 + l15;
                b[i] = *(const short8*)&sB[nr * 64 + (((kk >> 3) + quad + nr) & 7) * 8];
            }
            #pragma unroll
            for (int i = 0; i < 2; ++i)
                #pragma unroll
                for (int j = 0; j < 2; ++j)
                    acc[i][j] = __builtin_amdgcn_mfma_f32_16x16x32_bf16(
                        a[i], b[j], acc[i][j], 0, 0, 0);
        }
    }
    int rbase = bm * 64 + wm * 32 + quad * 4;
    int cbase = bn * 64 + wn * 32 + l15;
    #pragma unroll
    for (int i = 0; i < 2; ++i)
        #pragma unroll
        for (int r = 0; r < 4; ++r) {
            int gr = rbase + i * 16 + r;
            unsigned short* crow = Cout + (size_t)gr * ldc + cbase;
            #pragma unroll
            for (int j = 0; j < 2; ++j) crow[j * 16] = f2bf(acc[i][j][r]);
        }
}

// ---------------- conv4 (causal, depthwise) + silu ----------------
// Strip-mined (16 tokens/block, register history) + R7: vectorized loads.
// Thread t owns 8 CONSECUTIVE channels [8t, 8t+8) of the first 2048 (short8
// load/store = 16 B/lane) plus scalar-tail channel 2048+t of the last 256.
// Replaces 9 scalar bf16 loads/stores per token-thread (128 B/wave each)
// with 1 short8 + 1 scalar (G13: hipcc never vectorizes bf16 itself).
__global__ __launch_bounds__(256) void conv_silu_kernel(
    const unsigned short* __restrict__ Z, const float* __restrict__ convW,
    const float* __restrict__ convB, unsigned short* __restrict__ xbc) {
    int blk = blockIdx.x;                  // 512 blocks: bi*256 + s
    int bi = blk >> 8, s = blk & 255;
    int t0 = s * CTOK;
    int tid = threadIdx.x;
    const int cv = tid * 8;          // vector channels [cv, cv+8) in [0,2048)
    const int cs = 2048 + tid;       // scalar channel in [2048,2304)
    const size_t rowZ = (size_t)(bi * SEQL) * NBIG + 2048;  // xBC col base
    float w0[8], w1[8], w2[8], w3[8], bs[8], h1[8], h2[8], h3[8];
    #pragma unroll
    for (int j = 0; j < 8; ++j) {
        int c = cv + j;
        w0[j] = convW[c];
        w1[j] = convW[CONVD + c];
        w2[j] = convW[2 * CONVD + c];
        w3[j] = convW[3 * CONVD + c];
        bs[j] = convB[c];
        h1[j] = 0.f; h2[j] = 0.f; h3[j] = 0.f;
    }
    float sw0 = convW[cs], sw1 = convW[CONVD + cs], sw2 = convW[2 * CONVD + cs],
          sw3 = convW[3 * CONVD + cs], sbs = convB[cs];
    float sh1 = 0.f, sh2 = 0.f, sh3 = 0.f;
    if (t0 >= 3) {   // t0==0 only for s==0 (history = causal zero-pad)
        short8 v3 = *(const short8*)&Z[rowZ + (size_t)(t0 - 3) * NBIG + cv];
        short8 v2 = *(const short8*)&Z[rowZ + (size_t)(t0 - 2) * NBIG + cv];
        short8 v1 = *(const short8*)&Z[rowZ + (size_t)(t0 - 1) * NBIG + cv];
        #pragma unroll
        for (int j = 0; j < 8; ++j) {
            h3[j] = bf2f((unsigned short)v3[j]);
            h2[j] = bf2f((unsigned short)v2[j]);
            h1[j] = bf2f((unsigned short)v1[j]);
        }
        sh3 = bf2f(Z[rowZ + (size_t)(t0 - 3) * NBIG + cs]);
        sh2 = bf2f(Z[rowZ + (size_t)(t0 - 2) * NBIG + cs]);
        sh1 = bf2f(Z[rowZ + (size_t)(t0 - 1) * NBIG + cs]);
    }
    for (int t = t0; t < t0 + CTOK; ++t) {
        size_t zr = rowZ + (size_t)t * NBIG;
        size_t xr = (size_t)(bi * SEQL + t) * CONVD;
        short8 v = *(const short8*)&Z[zr + cv];
        short8 o;
        #pragma unroll
        for (int j = 0; j < 8; ++j) {
            float cur = bf2f((unsigned short)v[j]);
            float a = bs[j] + w0[j] * h3[j] + w1[j] * h2[j]
                            + w2[j] * h1[j] + w3[j] * cur;
            h3[j] = h2[j]; h2[j] = h1[j]; h1[j] = cur;
            o[j] = (short)f2bf(a / (1.0f + expf(-a)));
        }
        *(short8*)&xbc[xr + cv] = o;
        float scur = bf2f(Z[zr + cs]);
        float sa = sbs + sw0 * sh3 + sw1 * sh2 + sw2 * sh1 + sw3 * scur;
        sh3 = sh2; sh2 = sh1; sh1 = scur;
        xbc[xr + cs] = f2bf(sa / (1.0f + expf(-sa)));
    }
}

// ================= SSD chunked scan =================
__global__ __launch_bounds__(256, 2) void chunk_intra_kernel(
    const unsigned short* __restrict__ xbc, const unsigned short* __restrict__ Z,
    const float* __restrict__ dt_bias, const float* __restrict__ A_log,
    unsigned short* __restrict__ TS, float* __restrict__ abuf,
    unsigned short* __restrict__ ym) {
    __shared__ __align__(16) unsigned short Xt[64 * SP];
    __shared__ __align__(16) unsigned short Xw[64 * SP];
    __shared__ __align__(16) unsigned short BtM[128 * SP];
    __shared__ float dt_lds[128], dtA_lds[128], cum_lds[128], w_lds[128];
    int tid = threadIdx.x;
    int kch = blockIdx.x, bh = blockIdx.y;
    int h = bh & 31, bi = bh >> 5;
    int tok0 = bi * SEQL + kch * CHT;
    const unsigned short* xb = xbc + (size_t)tok0 * CONVD;
    if (tid < 128) {
        float v = bf2f(Z[(size_t)(tok0 + tid) * NBIG + 4352 + h]) + dt_bias[h];
        float sp = (v > 20.f) ? v : log1pf(expf(v));
        dt_lds[tid] = sp;
        dtA_lds[tid] = -sp * expf(A_log[h]);
    }
    for (int seg = tid; seg < 128 * 16; seg += 256) {
        int s = seg & 127, nb = seg >> 7;
        short8 v = *(const short8*)&xb[(size_t)s * CONVD + 2048 + nb * 8];
        #pragma unroll
        for (int j = 0; j < 8; ++j) BtM[(nb * 8 + j) * SP + s] = (unsigned short)v[j];
    }
    for (int seg = tid; seg < 128 * 8; seg += 256) {
        int s = seg & 127, pb = seg >> 7;
        short8 v = *(const short8*)&xb[(size_t)s * CONVD + h * 64 + pb * 8];
        #pragma unroll
        for (int j = 0; j < 8; ++j) Xt[(pb * 8 + j) * SP + s] = (unsigned short)v[j];
    }
    __syncthreads();
    if (tid < 128) {
        int lw = tid & 63;
        float v = dtA_lds[tid];
        #pragma unroll
        for (int off = 1; off < 64; off <<= 1) {
            float o = __shfl_up(v, off, 64);
            if (lw >= off) v += o;
        }
        cum_lds[tid] = v;
    }
    __syncthreads();
    if (tid >= 64 && tid < 128) cum_lds[tid] += cum_lds[63];
    __syncthreads();
    if (tid < 128) {
        float cT = cum_lds[127];
        w_lds[tid] = __expf(cT - cum_lds[tid]) * dt_lds[tid];
        abuf[(size_t)(bh * NCH + kch) * 128 + tid] = __expf(cum_lds[tid]);
    }
    __syncthreads();
    for (int seg = tid; seg < 64 * 16; seg += 256) {
        int pp = seg >> 4, sb = seg & 15;
        short8 v = *(const short8*)&Xt[pp * SP + sb * 8];
        short8 o;
        #pragma unroll
        for (int j = 0; j < 8; ++j)
            o[j] = (short)f2bf(bf2f((unsigned short)v[j]) * w_lds[sb * 8 + j]);
        *(short8*)&Xw[pp * SP + sb * 8] = o;
    }
    __syncthreads();
    int lane = tid & 63, wv = tid >> 6;
    int quad = lane >> 4, l15 = lane & 15;
    {
        f32x4 acc[8] = {};
        for (int kk = 0; kk < 128; kk += 32) {
            short8 a = *(const short8*)&Xw[(16 * wv + l15) * SP + kk + quad * 8];
            #pragma unroll
            for (int jn = 0; jn < 8; ++jn) {
                short8 b = *(const short8*)&BtM[(16 * jn + l15) * SP + kk + quad * 8];
                acc[jn] = __builtin_amdgcn_mfma_f32_16x16x32_bf16(a, b, acc[jn], 0, 0, 0);
            }
        }
        size_t tsbase = (size_t)(bh * NCH + kch) * 8192;
        #pragma unroll
        for (int jn = 0; jn < 8; ++jn)
            #pragma unroll
            for (int r = 0; r < 4; ++r) {
                int pp = 16 * wv + quad * 4 + r, n = 16 * jn + l15;
                TS[tsbase + pp * 128 + n] = f2bf(acc[jn][r]);
            }
    }
    __syncthreads();
    {
        f32x4 g[2][8] = {};
        for (int kk = 0; kk < 128; kk += 32) {
            int co = 2176 + kk + quad * 8;
            short8 a0 = *(const short8*)&xb[(size_t)(32 * wv + l15) * CONVD + co];
            short8 a1 = *(const short8*)&xb[(size_t)(32 * wv + 16 + l15) * CONVD + co];
            int bo = 2048 + kk + quad * 8;
            #pragma unroll
            for (int js = 0; js < 8; ++js) {
                short8 b = *(const short8*)&xb[(size_t)(16 * js + l15) * CONVD + bo];
                g[0][js] = __builtin_amdgcn_mfma_f32_16x16x32_bf16(a0, b, g[0][js], 0, 0, 0);
                g[1][js] = __builtin_amdgcn_mfma_f32_16x16x32_bf16(a1, b, g[1][js], 0, 0, 0);
            }
        }
        #pragma unroll
        for (int it = 0; it < 2; ++it)
            #pragma unroll
            for (int js = 0; js < 8; ++js) {
                int s = 16 * js + l15;
                float cs = cum_lds[s], ds = dt_lds[s];
                #pragma unroll
                for (int r = 0; r < 4; ++r) {
                    int t = 32 * wv + 16 * it + quad * 4 + r;
                    float f = (s <= t) ? __expf(cum_lds[t] - cs) * ds : 0.f;
                    BtM[t * SP + s] = f2bf(g[it][js][r] * f);
                }
            }
    }
    __syncthreads();
    {
        f32x4 y[2][4] = {};
        for (int kk = 0; kk < 128; kk += 32) {
            short8 a0 = *(const short8*)&BtM[(32 * wv + l15) * SP + kk + quad * 8];
            short8 a1 = *(const short8*)&BtM[(32 * wv + 16 + l15) * SP + kk + quad * 8];
            #pragma unroll
            for (int jp = 0; jp < 4; ++jp) {
                short8 b = *(const short8*)&Xt[(16 * jp + l15) * SP + kk + quad * 8];
                y[0][jp] = __builtin_amdgcn_mfma_f32_16x16x32_bf16(a0, b, y[0][jp], 0, 0, 0);
                y[1][jp] = __builtin_amdgcn_mfma_f32_16x16x32_bf16(a1, b, y[1][jp], 0, 0, 0);
            }
        }
        #pragma unroll
        for (int it = 0; it < 2; ++it)
            #pragma unroll
            for (int jp = 0; jp < 4; ++jp)
                #pragma unroll
                for (int r = 0; r < 4; ++r) {
                    int t = 32 * wv + 16 * it + quad * 4 + r;
                    int pp = 16 * jp + l15;
                    ym[(size_t)(tok0 + t) * DIN + h * 64 + pp] = f2bf(y[it][jp][r]);
                }
    }
}

__global__ __launch_bounds__(128) void state_recur_kernel(
    unsigned short* __restrict__ TS, const float* __restrict__ abuf) {
    int bh = blockIdx.x >> 6, p = blockIdx.x & 63, n = threadIdx.x;
    float s = 0.f;
    for (int k = 0; k < NCH; ++k) {
        size_t base = ((size_t)(bh * NCH + k) * 64 + p) * 128 + n;
        float aT = abuf[(size_t)(bh * NCH + k) * 128 + 127];
        float tv = bf2f(TS[base]);
        TS[base] = f2bf(s);
        s = fmaf(aT, s, tv);
    }
}

__global__ __launch_bounds__(256) void chunk_inter_kernel(
    const unsigned short* __restrict__ xbc, const unsigned short* __restrict__ TS,
    const float* __restrict__ abuf, const float* __restrict__ Dp,
    unsigned short* ym) {
    __shared__ float a_ld[128];
    int tid = threadIdx.x;
    int kch = blockIdx.x, bh = blockIdx.y;
    int h = bh & 31, bi = bh >> 5;
    int tok0 = bi * SEQL + kch * CHT;
    if (tid < 128) a_ld[tid] = abuf[(size_t)(bh * NCH + kch) * 128 + tid];
    __syncthreads();
    int lane = tid & 63, wv = tid >> 6;
    int quad = lane >> 4, l15 = lane & 15;
    const unsigned short* xb = xbc + (size_t)tok0 * CONVD;
    size_t tsbase = (size_t)(bh * NCH + kch) * 8192;
    int t0 = 32 * wv + l15, t1 = t0 + 16;
    float at0 = a_ld[t0], at1 = a_ld[t1];
    f32x4 y[2][4] = {};
    for (int kk = 0; kk < 128; kk += 32) {
        int co = 2176 + kk + quad * 8;
        short8 c0 = *(const short8*)&xb[(size_t)t0 * CONVD + co];
        short8 c1 = *(const short8*)&xb[(size_t)t1 * CONVD + co];
        short8 a0, a1;
        #pragma unroll
        for (int j = 0; j < 8; ++j) {
            a0[j] = (short)f2bf(bf2f((unsigned short)c0[j]) * at0);
            a1[j] = (short)f2bf(bf2f((unsigned short)c1[j]) * at1);
        }
        #pragma unroll
        for (int jp = 0; jp < 4; ++jp) {
            short8 b = *(const short8*)&TS[tsbase + (size_t)(16 * jp + l15) * 128 + kk + quad * 8];
            y[0][jp] = __builtin_amdgcn_mfma_f32_16x16x32_bf16(a0, b, y[0][jp], 0, 0, 0);
            y[1][jp] = __builtin_amdgcn_mfma_f32_16x16x32_bf16(a1, b, y[1][jp], 0, 0, 0);
        }
    }
    float Dh = Dp[h];
    #pragma unroll
    for (int it = 0; it < 2; ++it)
        #pragma unroll
        for (int jp = 0; jp < 4; ++jp)
            #pragma unroll
            for (int r = 0; r < 4; ++r) {
                int t = 32 * wv + 16 * it + quad * 4 + r;
                int pp = 16 * jp + l15;
                size_t yi = (size_t)(tok0 + t) * DIN + h * 64 + pp;
                float xv = bf2f(xb[(size_t)t * CONVD + h * 64 + pp]);
                float yv = y[it][jp][r] + bf2f(ym[yi]) + Dh * xv;
                ym[yi] = f2bf(yv);
            }
}

// ---------------- gated rmsnorm ----------------
__global__ __launch_bounds__(256) void gated_norm_kernel(
    const unsigned short* __restrict__ y,
    const unsigned short* __restrict__ Z,
    const float* __restrict__ gw, unsigned short* mamba) {
    int tok = blockIdx.x, tid = threadIdx.x;
    float vals[8];
    float ss = 0;
    #pragma unroll
    for (int i = 0; i < 8; ++i) {
        int c = tid + i * 256;
        float yv = bf2f(y[(size_t)tok * DIN + c]);
        float zv = bf2f(Z[(size_t)tok * NBIG + c]);
        float g = yv * (zv / (1.0f + expf(-zv)));
        vals[i] = g;
        ss += g * g;
    }
    #pragma unroll
    for (int off = 32; off > 0; off >>= 1) ss += __shfl_xor(ss, off, 64);
    __shared__ float sred[4];
    if ((tid & 63) == 0) sred[tid >> 6] = ss;
    __syncthreads();
    float tot = sred[0] + sred[1] + sred[2] + sred[3];
    float r = rsqrtf(tot * (1.0f / DIN) + 1e-5f);
    #pragma unroll
    for (int i = 0; i < 8; ++i) {
        int c = tid + i * 256;
        mamba[(size_t)tok * DIN + c] = f2bf(vals[i] * r * gw[c]);
    }
}

// ---------------- chunked cumsum over L of Q ----------------
__global__ void cumsum_pass1_kernel(const unsigned short* __restrict__ Z,
                                    float* __restrict__ S) {
    int cg = blockIdx.x & 3, ch = (blockIdx.x >> 2) & 31, bi = blockIdx.x >> 7;
    int c = cg * 256 + threadIdx.x;
    size_t base = (size_t)(bi * SEQL + ch * 128) * NBIG;
    float s = 0;
    for (int t = 0; t < 128; ++t)
        s += bf2f(Z[base + (size_t)t * NBIG + 5408 + c]);
    S[(bi * 32 + ch) * 1024 + c] = s;
}

__global__ void cumsum_pass2_kernel(unsigned short* __restrict__ Z,
                                    const float* __restrict__ S) {
    int cg = blockIdx.x & 3, ch = (blockIdx.x >> 2) & 31, bi = blockIdx.x >> 7;
    int c = cg * 256 + threadIdx.x;
    float run = 0;
    for (int k = 0; k < ch; ++k) run += S[(bi * 32 + k) * 1024 + c];
    size_t base = (size_t)(bi * SEQL + ch * 128) * NBIG;
    for (int t = 0; t < 128; ++t) {
        size_t row = base + (size_t)t * NBIG;
        run += bf2f(Z[row + 5408 + c]);
        ((float*)(Z + row))[c] = run;
    }
}

// ---------------- launch ----------------
extern "C" void kernel_launch(void* const* d_in, const int* in_sizes, int n_in,
                              void* d_out, int out_size, void* d_ws, size_t ws_size,
                              hipStream_t stream) {
    (void)in_sizes; (void)n_in; (void)out_size; (void)ws_size;
    const float* x        = (const float*)d_in[0];
    const float* norm_w   = (const float*)d_in[1];
    const float* in_projW = (const float*)d_in[2];
    const float* conv_W   = (const float*)d_in[3];
    const float* conv_b   = (const float*)d_in[4];
    const float* dt_bias  = (const float*)d_in[5];
    const float* A_log    = (const float*)d_in[6];
    const float* Dp       = (const float*)d_in[7];
    const float* gnorm_w  = (const float*)d_in[8];
    const float* zero_W   = (const float*)d_in[9];
    const float* one_W    = (const float*)d_in[10];
    const float* fusion_W = (const float*)d_in[11];
    float* out = (float*)d_out;

    char* p = (char*)d_ws;
    auto alloc = [&](size_t bytes) { char* r = p; p += (bytes + 255) & ~(size_t)255; return r; };
    unsigned short* Wf_t  = (unsigned short*)alloc((size_t)DMODEL * 6144 * 2);
    char* pool0 = p;
    unsigned short* xn_bf = (unsigned short*)alloc((size_t)NTOT * DMODEL * 2);
    unsigned short* zWb   = (unsigned short*)alloc((size_t)DMODEL * DIN * 2);
    unsigned short* oWb   = (unsigned short*)alloc((size_t)DMODEL * DIN * 2);
    unsigned short* Bt    = (unsigned short*)alloc((size_t)NPAD * DMODEL * 2);  // 6656 rows
    unsigned short* xbc   = (unsigned short*)pool0;  // alias over dead prep pool
    float* abuf = (float*)alloc((size_t)64 * NCH * 128 * 4);
    float* Sb   = (float*)alloc((size_t)2 * 32 * 1024 * 4);
    unsigned short* ym  = (unsigned short*)alloc((size_t)NTOT * DIN * 2);
    unsigned short* Zbf = (unsigned short*)alloc((size_t)NTOT * NBIG * 2);
    unsigned short* TS = (unsigned short*)d_out;  // 33.5MB exact fit; dead before final GEMM

    transpose_cast_kernel<<<dim3(DPROJ / 32, DMODEL / 32), dim3(32, 8), 0, stream>>>(
        in_projW, Bt, DMODEL, DPROJ);
    transpose_cast_kernel<<<dim3(DMODEL / 32, 6144 / 32), dim3(32, 8), 0, stream>>>(
        fusion_W, Wf_t, 6144, DMODEL);
    cast_bf16_kernel<<<2048, 256, 0, stream>>>(zero_W, zWb, DMODEL * DIN);
    cast_bf16_kernel<<<2048, 256, 0, stream>>>(one_W, oWb, DMODEL * DIN);
    zero_pad_kernel<<<(NPAD - NREAL) * DMODEL / 256, 256, 0, stream>>>(
        Bt + (size_t)NREAL * DMODEL, (NPAD - NREAL) * DMODEL);

    rmsnorm_cast_kernel<<<NTOT, 256, 0, stream>>>(x, norm_w, xn_bf);

    // Mzero^T, Mone^T into Bt rows [4384,6432) — both in one z=2 launch
    gemm64_kernel<<<dim3(16, 16, 2), 256, 0, stream>>>(
        Wf_t + 2048, Wf_t + 4096, 6144,
        zWb, oWb, DIN,
        Bt + (size_t)4384 * DMODEL, Bt + (size_t)5408 * DMODEL, DMODEL, DIN);

    // big projection GEMM: 256x256 8-phase pipeline (stores guarded at NBIG)
    gemm256_kernel<<<dim3(NPAD / 256, NTOT / 256), 512, 0, stream>>>(
        xn_bf, DMODEL, Bt, DMODEL, Zbf, NBIG, DMODEL, NBIG);

    conv_silu_kernel<<<512, 256, 0, stream>>>(Zbf, conv_W, conv_b, xbc);

    chunk_intra_kernel<<<dim3(NCH, 64), 256, 0, stream>>>(
        xbc, Zbf, dt_bias, A_log, TS, abuf, ym);
    state_recur_kernel<<<64 * 64, 128, 0, stream>>>(TS, abuf);
    chunk_inter_kernel<<<dim3(NCH, 64), 256, 0, stream>>>(
        xbc, TS, abuf, Dp, ym);

    gated_norm_kernel<<<NTOT, 256, 0, stream>>>(ym, Zbf, gnorm_w, ym);

    cumsum_pass1_kernel<<<256, 256, 0, stream>>>(Zbf, Sb);
    cumsum_pass2_kernel<<<256, 256, 0, stream>>>(Zbf, Sb);

    gemm_bt_kernel<2><<<dim3(DMODEL / 128, NTOT / 128), 256, 0, stream>>>(
        ym, DIN, Wf_t, 6144, out, DMODEL, DIN, x, Zbf);
}